// Round 7
// baseline (355.461 us; speedup 1.0000x reference)
//
#include <hip/hip_runtime.h>
#include <hip/hip_bf16.h>
#include <cstdint>
#include <cmath>

typedef __bf16 bf16x8 __attribute__((ext_vector_type(8)));
typedef float  f32x4  __attribute__((ext_vector_type(4)));
typedef unsigned short u16x8 __attribute__((ext_vector_type(8)));

#define BT 128   // tile M and N (legacy 128^2 kernel, used for GEMM3)
#define BK 64    // tile K

__device__ __forceinline__ float bf2f(unsigned short h) {
  union { unsigned int u; float f; } v; v.u = ((unsigned int)h) << 16;
  return v.f;
}
__device__ __forceinline__ unsigned short f2bf(float x) {
  union { float f; unsigned int u; } v; v.f = x;
  unsigned int r = v.u + 0x7fffu + ((v.u >> 16) & 1u);  // RNE
  return (unsigned short)(r >> 16);
}

__device__ __forceinline__ void gld_lds16(const void* g, void* l) {
  __builtin_amdgcn_global_load_lds(
      (const __attribute__((address_space(1))) unsigned int*)g,
      (__attribute__((address_space(3))) unsigned int*)l,
      16, 0, 0);
}

__device__ __forceinline__ void cvt4(const float* __restrict__ in,
                                     unsigned short* __restrict__ out, int i) {
  float4 v = reinterpret_cast<const float4*>(in)[i];
  ushort4 o;
  o.x = f2bf(v.x); o.y = f2bf(v.y); o.z = f2bf(v.z); o.w = f2bf(v.w);
  reinterpret_cast<ushort4*>(out)[i] = o;
}

// Head: convert x (8192 blocks) and W_in (4096 blocks) in one launch.
__global__ void cvt_head(const float* __restrict__ x, unsigned short* __restrict__ xb,
                         const float* __restrict__ W_in, unsigned short* __restrict__ wb) {
  int b = blockIdx.x;
  if (b < 8192) cvt4(x, xb, b * 256 + threadIdx.x);
  else          cvt4(W_in, wb, (b - 8192) * 256 + threadIdx.x);
}

// Conv strip: thread owns 8 channels x 32 rows, 3-tap history in registers.
__device__ void conv_strip(const unsigned short* __restrict__ xz,
                           const float* __restrict__ conv_w,
                           const float* __restrict__ conv_b,
                           unsigned short* __restrict__ xc,
                           int strip, int tid) {
  const int bl0  = strip * 32;
  const int seq0 = bl0 & ~4095;      // sequence start (B=2, L=4096)
  const int c0   = tid * 8;
  float w[4][8], bb[8];
#pragma unroll
  for (int j = 0; j < 8; ++j) {
    float4 wr = reinterpret_cast<const float4*>(conv_w)[c0 + j];
    w[0][j] = wr.x; w[1][j] = wr.y; w[2][j] = wr.z; w[3][j] = wr.w;
    bb[j] = conv_b[c0 + j];
  }
  float win[3][8];
#pragma unroll
  for (int i = 0; i < 3; ++i) {
    int r = bl0 - 3 + i;
    if (r >= seq0) {
      u16x8 v = *reinterpret_cast<const u16x8*>(xz + (size_t)r * 4096 + c0);
#pragma unroll
      for (int j = 0; j < 8; ++j) win[i][j] = bf2f(v[j]);
    } else {
#pragma unroll
      for (int j = 0; j < 8; ++j) win[i][j] = 0.f;
    }
  }
  for (int i = 0; i < 32; ++i) {
    const int bl = bl0 + i;
    u16x8 v = *reinterpret_cast<const u16x8*>(xz + (size_t)bl * 4096 + c0);
    u16x8 o;
#pragma unroll
    for (int j = 0; j < 8; ++j) {
      float cur = bf2f(v[j]);
      float a = bb[j] + w[0][j] * win[0][j] + w[1][j] * win[1][j]
                      + w[2][j] * win[2][j] + w[3][j] * cur;
      o[j] = f2bf(a / (1.f + __expf(-a)));
      win[0][j] = win[1][j]; win[1][j] = win[2][j]; win[2][j] = cur;
    }
    *reinterpret_cast<u16x8*>(xc + (size_t)bl * 2048 + c0) = o;
  }
}

// Mid: conv_silu + W_xproj cvt + W_out cvt, one launch.
__global__ void mid_fused(const unsigned short* __restrict__ xz,
                          const float* __restrict__ conv_w,
                          const float* __restrict__ conv_b,
                          unsigned short* __restrict__ xc,
                          const float* __restrict__ W_xproj, unsigned short* __restrict__ wx_bf,
                          const float* __restrict__ W_out,   unsigned short* __restrict__ wo_bf) {
  int b = blockIdx.x;
  if (b < 256) { conv_strip(xz, conv_w, conv_b, xc, b, threadIdx.x); return; }
  b -= 256;
  if (b < 4160) { cvt4(W_xproj, wx_bf, b * 256 + threadIdx.x); return; }
  cvt4(W_out, wo_bf, (b - 4160) * 256 + threadIdx.x);
}

// ---------------------------------------------------------------------------
// Legacy 128^2 kernel (m97 structure) — kept for GEMM3 (N=1024: 512 blocks).
// ---------------------------------------------------------------------------
template <int GUARD_N, int OUT_F32>
__global__ __launch_bounds__(256, 2)
void gemm_bt(const unsigned short* __restrict__ A,
             const unsigned short* __restrict__ B,
             void* __restrict__ Cv,
             int N, int K, int ldA, int ldB, int ldC)
{
  __shared__ __align__(16) unsigned short sA[BT * BK];
  __shared__ __align__(16) unsigned short sB[BT * BK];

  const int tid  = threadIdx.x;
  const int lane = tid & 63;
  const int wave = tid >> 6;
  const int row0 = blockIdx.x * BT;
  const int col0 = blockIdx.y * BT;

  const int wrow = (wave & 1) * 64;
  const int wcol = (wave >> 1) * 64;
  const int l15  = lane & 15;
  const int q    = lane >> 4;

  f32x4 acc[4][4];
#pragma unroll
  for (int i = 0; i < 4; ++i)
#pragma unroll
    for (int j = 0; j < 4; ++j)
      acc[i][j] = (f32x4){0.f, 0.f, 0.f, 0.f};

  const int nk = K / BK;
  for (int kt = 0; kt < nk; ++kt) {
    const int k0 = kt * BK;
#pragma unroll
    for (int t = 0; t < 4; ++t) {
      int c  = t * 256 + tid;
      int r  = c >> 3;
      int g  = c & 7;
      int gs = (g ^ (r & 7)) * 8;
      gld_lds16(A + (size_t)(row0 + r) * ldA + k0 + gs, (void*)(sA + c * 8));
      int br = col0 + r;
      if (GUARD_N) br = (br < N) ? br : (N - 1);
      gld_lds16(B + (size_t)br * ldB + k0 + gs, (void*)(sB + c * 8));
    }
    __syncthreads();

#pragma unroll
    for (int kk = 0; kk < BK; kk += 32) {
      const int grb = kk >> 3;
      bf16x8 af[4], bfr[4];
#pragma unroll
      for (int i = 0; i < 4; ++i) {
        int ar = wrow + i * 16 + l15;
        af[i] = *reinterpret_cast<const bf16x8*>(
            sA + ar * BK + (((grb + q) ^ (ar & 7)) << 3));
        int br = wcol + i * 16 + l15;
        bfr[i] = *reinterpret_cast<const bf16x8*>(
            sB + br * BK + (((grb + q) ^ (br & 7)) << 3));
      }
#pragma unroll
      for (int i = 0; i < 4; ++i)
#pragma unroll
        for (int j = 0; j < 4; ++j)
          acc[i][j] = __builtin_amdgcn_mfma_f32_16x16x32_bf16(af[i], bfr[j], acc[i][j], 0, 0, 0);
    }
    __syncthreads();
  }

#pragma unroll
  for (int i = 0; i < 4; ++i) {
#pragma unroll
    for (int j = 0; j < 4; ++j) {
      int colw = col0 + wcol + j * 16 + l15;
      if (GUARD_N && colw >= N) continue;
#pragma unroll
      for (int r = 0; r < 4; ++r) {
        int roww = row0 + wrow + i * 16 + q * 4 + r;
        if (OUT_F32)
          ((float*)Cv)[(size_t)roww * ldC + colw] = acc[i][j][r];
        else
          ((unsigned short*)Cv)[(size_t)roww * ldC + colw] = f2bf(acc[i][j][r]);
      }
    }
  }
}

// ---------------------------------------------------------------------------
// 256x256 GEMM, 4-barriers-per-K-tile. Phase = {BARX; STAGE; RD(next); MFMA}.
// Correctness rules used (from R4 failure + per-wave vmcnt semantics):
//  (1) 2-phase rule: ds_reads issued in phase X are globally drained once all
//      waves cross the barrier at start of X+2 (MFMA(X+1) consumes them, so
//      each wave's lgkm wait precedes that barrier). Every STAGE below
//      overwrites only regions whose last read was >= 2 phases earlier:
//        - STAGE_A(nb) @P0/P1: buf nb A last read P2 of prev tile (drained at
//          this tile's P0 barrier). New A-p0 read at P3, after VMW+BARX.
//        - STAGE_B(cb) @P1/P2: buf cb B last LDS-read at prev tile P3
//          (drained at this tile's P1 barrier).
//  (2) vmcnt is PER-WAVE: VMW(N) must precede the barrier that precedes the
//      dependent reads (barrier globalizes the drain). Ledger: at P2-end a
//      wave has 12 loads in flight {B(t+1):4 oldest, A(t+1):4, B(t+2):4};
//      VMW(4) drains the 8 that P3 reads, leaves B(t+2).
// Epilogue: LDS-staged coalesced store, with q-XOR on col bits 4-5 so the 4
// q-groups of a wave hit all 32 banks (fixes R5's 2^20 write conflicts).
// ---------------------------------------------------------------------------
#define BARX() do { __builtin_amdgcn_sched_barrier(0); \
                    __builtin_amdgcn_s_barrier(); \
                    __builtin_amdgcn_sched_barrier(0); } while (0)
#define VMW(n) asm volatile("s_waitcnt vmcnt(" #n ")" ::: "memory")
#define LGKM0() asm volatile("s_waitcnt lgkmcnt(0)" ::: "memory")

#define STAGE_A(b, h, kt) do { \
  const unsigned short* _p = Ab + (size_t)((h) * 128) * ldA + (kt) * 64; \
  gld_lds16(_p,                     (void*)&sA[b][((h) * 128      + rr) * 64 + (g8 << 3)]); \
  gld_lds16(_p + (size_t)64 * ldA,  (void*)&sA[b][((h) * 128 + 64 + rr) * 64 + (g8 << 3)]); \
} while (0)

#define STAGE_B(b, h, kt) do { \
  const unsigned short* _p = Bb + (size_t)((h) * 128) * ldB + (kt) * 64; \
  gld_lds16(_p,                     (void*)&sB[b][((h) * 128      + rr) * 64 + (g8 << 3)]); \
  gld_lds16(_p + (size_t)64 * ldB,  (void*)&sB[b][((h) * 128 + 64 + rr) * 64 + (g8 << 3)]); \
} while (0)

#define RD_A_SET(dst, b, p) do { \
  dst[0][0] = *reinterpret_cast<const bf16x8*>(&sA[b][aOff + (2*(p)    ) * 1024 + kph0]); \
  dst[0][1] = *reinterpret_cast<const bf16x8*>(&sA[b][aOff + (2*(p)    ) * 1024 + kph1]); \
  dst[1][0] = *reinterpret_cast<const bf16x8*>(&sA[b][aOff + (2*(p) + 1) * 1024 + kph0]); \
  dst[1][1] = *reinterpret_cast<const bf16x8*>(&sA[b][aOff + (2*(p) + 1) * 1024 + kph1]); \
} while (0)

#define RD_B_SET(dst, b) do { \
  dst[0][0] = *reinterpret_cast<const bf16x8*>(&sB[b][bOff + 0 * 1024 + kph0]); \
  dst[0][1] = *reinterpret_cast<const bf16x8*>(&sB[b][bOff + 0 * 1024 + kph1]); \
  dst[1][0] = *reinterpret_cast<const bf16x8*>(&sB[b][bOff + 1 * 1024 + kph0]); \
  dst[1][1] = *reinterpret_cast<const bf16x8*>(&sB[b][bOff + 1 * 1024 + kph1]); \
  dst[2][0] = *reinterpret_cast<const bf16x8*>(&sB[b][bOff + 2 * 1024 + kph0]); \
  dst[2][1] = *reinterpret_cast<const bf16x8*>(&sB[b][bOff + 2 * 1024 + kph1]); \
  dst[3][0] = *reinterpret_cast<const bf16x8*>(&sB[b][bOff + 3 * 1024 + kph0]); \
  dst[3][1] = *reinterpret_cast<const bf16x8*>(&sB[b][bOff + 3 * 1024 + kph1]); \
} while (0)

#define MMA(i, j, k, Af, Bf) \
  acc[i][j] = __builtin_amdgcn_mfma_f32_16x16x32_bf16(Af[(i) & 1][k], Bf[j][k], acc[i][j], 0, 0, 0)

// 16 MFMA, dependency distance 8: all 8 accs at k-half 0, then k-half 1.
#define MFMA_PH(p, Af, Bf) do { \
  __builtin_amdgcn_s_setprio(1); \
  MMA(2*(p),   0, 0, Af, Bf); MMA(2*(p),   1, 0, Af, Bf); \
  MMA(2*(p),   2, 0, Af, Bf); MMA(2*(p),   3, 0, Af, Bf); \
  MMA(2*(p)+1, 0, 0, Af, Bf); MMA(2*(p)+1, 1, 0, Af, Bf); \
  MMA(2*(p)+1, 2, 0, Af, Bf); MMA(2*(p)+1, 3, 0, Af, Bf); \
  MMA(2*(p),   0, 1, Af, Bf); MMA(2*(p),   1, 1, Af, Bf); \
  MMA(2*(p),   2, 1, Af, Bf); MMA(2*(p),   3, 1, Af, Bf); \
  MMA(2*(p)+1, 0, 1, Af, Bf); MMA(2*(p)+1, 1, 1, Af, Bf); \
  MMA(2*(p)+1, 2, 1, Af, Bf); MMA(2*(p)+1, 3, 1, Af, Bf); \
  __builtin_amdgcn_s_setprio(0); \
} while (0)

__global__ __launch_bounds__(512, 2)
void gemm256(const unsigned short* __restrict__ A,
             const unsigned short* __restrict__ B,
             unsigned short* __restrict__ C,
             int K, int ldA, int ldB, int ldC, int ccsh)
{
  __shared__ __align__(16) unsigned short smem[4 * 256 * 64];  // 128 KiB
  unsigned short (*sA)[256 * 64] = (unsigned short (*)[256 * 64])smem;
  unsigned short (*sB)[256 * 64] = (unsigned short (*)[256 * 64])(smem + 2 * 256 * 64);

  const int tid  = threadIdx.x;
  const int lane = tid & 63;
  const int wave = tid >> 6;
  const int wm = wave >> 2;      // 0..1
  const int wn = wave & 3;       // 0..3
  const int l15 = lane & 15;
  const int q   = lane >> 4;

  // Chunked XCD swizzle: XCD x owns an R x CC chunk of output tiles;
  // XCD grid = 2 chunk-cols x 4 chunk-rows. Bijective for nwg%8==0.
  const int nwg = gridDim.x;
  const int wg  = blockIdx.x;
  const int x   = wg & 7;
  const int c   = wg >> 3;
  const int CC  = 1 << ccsh;
  const int R   = (nwg >> 3) >> ccsh;
  const int row0 = ((x >> 1) * R + (c >> ccsh)) * 256;
  const int col0 = ((x & 1) * CC + (c & (CC - 1))) * 256;

  // staging geometry: thread covers row rr (+64 per 2nd load), k-group g8;
  // LDS slot (r,g) holds global k-group g^(r&7) -> pre-swizzled global source
  const int rr  = tid >> 3;
  const int g8  = tid & 7;
  const int gsw = ((g8 ^ (rr & 7)) << 3);
  const unsigned short* Ab = A + (size_t)(row0 + rr) * ldA + gsw;
  const unsigned short* Bb = B + (size_t)(col0 + rr) * ldB + gsw;

  // ds-read geometry
  const int aOff = (wm * 128 + l15) * 64;
  const int bOff = (wn * 64  + l15) * 64;
  const int a7   = l15 & 7;
  const int kph0 = ((q       ^ a7) << 3);  // k-groups 0..3 (kk=0)
  const int kph1 = (((4 + q) ^ a7) << 3);  // k-groups 4..7 (kk=32)

  f32x4 acc[8][4];
#pragma unroll
  for (int i = 0; i < 8; ++i)
#pragma unroll
    for (int j = 0; j < 4; ++j)
      acc[i][j] = (f32x4){0.f, 0.f, 0.f, 0.f};

  bf16x8 afe[2][2], afo[2][2];   // A fragments, phase-parity double buffer
  bf16x8 bfe[4][2], bfo[4][2];   // B fragments, K-tile-parity double buffer

  const int nk = K >> 6;
  // Prologue: tile0 A+B into buf0, tile1 B into buf1 (12 loads); drain tile0
  // (VMW(4) leaves tile1's B in flight), prime regs for tile0 phase 0.
  STAGE_A(0, 0, 0); STAGE_A(0, 1, 0);
  STAGE_B(0, 0, 0); STAGE_B(0, 1, 0);
  STAGE_B(1, 0, 1); STAGE_B(1, 1, 1);
  VMW(4);
  BARX();
  RD_B_SET(bfe, 0); RD_A_SET(afe, 0, 0);

  const int niter = K >> 7;
  for (int it = 0; it < niter; ++it) {
    const int ktA0 = 2 * it + 1;                          // A for odd tile (always < nk)
    int kt2 = 2 * it + 2; if (kt2 > nk - 1) kt2 = nk - 1; // tile t+2 (clamped tail)
    int kt3 = 2 * it + 3; if (kt3 > nk - 1) kt3 = nk - 1; // tile t+3 (clamped tail)

    // ---- even K-tile (buf0, bfe): stage A(buf1)@ktA0, B(buf0)@kt2 ----
    BARX();
    STAGE_A(1, 0, ktA0);
    RD_A_SET(afo, 0, 1); MFMA_PH(0, afe, bfe);
    BARX();
    STAGE_A(1, 1, ktA0); STAGE_B(0, 0, kt2);
    RD_A_SET(afe, 0, 2); MFMA_PH(1, afo, bfe);
    BARX();
    STAGE_B(0, 1, kt2);
    RD_A_SET(afo, 0, 3); MFMA_PH(2, afe, bfe);
    VMW(4);
    BARX();
    RD_B_SET(bfo, 1); RD_A_SET(afe, 1, 0); MFMA_PH(3, afo, bfe);

    // ---- odd K-tile (buf1, bfo): stage A(buf0)@kt2, B(buf1)@kt3 ----
    BARX();
    STAGE_A(0, 0, kt2);
    RD_A_SET(afo, 1, 1); MFMA_PH(0, afe, bfo);
    BARX();
    STAGE_A(0, 1, kt2); STAGE_B(1, 0, kt3);
    RD_A_SET(afe, 1, 2); MFMA_PH(1, afo, bfo);
    BARX();
    STAGE_B(1, 1, kt3);
    RD_A_SET(afo, 1, 3); MFMA_PH(2, afe, bfo);
    VMW(4);
    BARX();
    RD_B_SET(bfe, 0); RD_A_SET(afe, 0, 0); MFMA_PH(3, afo, bfo);
  }

  // ---- Epilogue: drain everything, stage C tile in LDS, coalesced store ----
  VMW(0);
  LGKM0();
  BARX();
  {
    unsigned short* cs = smem;  // 65536 ushorts = one 256x256 bf16 C tile
    // q-XOR on col bits 4-5: write banks = (j^q) groups -> all 32 banks/wave.
#pragma unroll
    for (int i = 0; i < 8; ++i) {
      const int row = wm * 128 + i * 16 + q * 4;
#pragma unroll
      for (int j = 0; j < 4; ++j) {
        const int col = (wn * 64 + j * 16 + l15) ^ (q << 4);
#pragma unroll
        for (int r = 0; r < 4; ++r)
          cs[(row + r) * 256 + col] = f2bf(acc[i][j][r]);
      }
    }
    LGKM0();   // ds_writes committed before signaling
    BARX();
#pragma unroll
    for (int s = 0; s < 16; ++s) {
      const int u   = s * 4096 + tid * 8;   // ushort index, 16B per thread
      const int row = u >> 8;
      const int col = u & 255;
      const int rcol = col ^ (((row >> 2) & 3) << 4);  // inverse of write XOR
      u16x8 v = *reinterpret_cast<const u16x8*>(&cs[row * 256 + rcol]);
      *reinterpret_cast<u16x8*>(C + (size_t)(row0 + row) * ldC + col0 + col) = v;
    }
  }
}

// ---------------------------------------------------------------------------
// proj strip: proj[:, 0:32] = xc @ W_xproj[0:32]^T. Memory-bound (reads xc
// once, 33.5 MB). Block = 32 rows, 4 waves split K=2048 into 512 each,
// fp32 LDS reduction, bf16 out. Grid 256 -> all CUs.
// ---------------------------------------------------------------------------
__global__ __launch_bounds__(256)
void proj_strip(const unsigned short* __restrict__ xc,   // [8192][2048]
                const unsigned short* __restrict__ wx,   // [2080][2048], rows 0..31
                unsigned short* __restrict__ proj)       // [8192][2080]
{
  __shared__ float red[4][32 * 32];
  const int tid  = threadIdx.x;
  const int lane = tid & 63;
  const int wave = tid >> 6;
  const int l15  = lane & 15;
  const int q    = lane >> 4;
  const int row0 = blockIdx.x * 32;

  f32x4 acc[2][2];
#pragma unroll
  for (int i = 0; i < 2; ++i)
#pragma unroll
    for (int j = 0; j < 2; ++j) acc[i][j] = (f32x4){0.f, 0.f, 0.f, 0.f};

  const int kbase = wave * 512;
#pragma unroll 4
  for (int kk = 0; kk < 512; kk += 32) {
    const int k = kbase + kk + q * 8;
    bf16x8 a0 = *reinterpret_cast<const bf16x8*>(&xc[(size_t)(row0 + l15) * 2048 + k]);
    bf16x8 a1 = *reinterpret_cast<const bf16x8*>(&xc[(size_t)(row0 + 16 + l15) * 2048 + k]);
    bf16x8 b0 = *reinterpret_cast<const bf16x8*>(&wx[(size_t)(l15) * 2048 + k]);
    bf16x8 b1 = *reinterpret_cast<const bf16x8*>(&wx[(size_t)(16 + l15) * 2048 + k]);
    acc[0][0] = __builtin_amdgcn_mfma_f32_16x16x32_bf16(a0, b0, acc[0][0], 0, 0, 0);
    acc[0][1] = __builtin_amdgcn_mfma_f32_16x16x32_bf16(a0, b1, acc[0][1], 0, 0, 0);
    acc[1][0] = __builtin_amdgcn_mfma_f32_16x16x32_bf16(a1, b0, acc[1][0], 0, 0, 0);
    acc[1][1] = __builtin_amdgcn_mfma_f32_16x16x32_bf16(a1, b1, acc[1][1], 0, 0, 0);
  }

#pragma unroll
  for (int i = 0; i < 2; ++i)
#pragma unroll
    for (int j = 0; j < 2; ++j)
#pragma unroll
      for (int r = 0; r < 4; ++r)
        red[wave][(i * 16 + q * 4 + r) * 32 + j * 16 + l15] = acc[i][j][r];
  __syncthreads();

#pragma unroll
  for (int t = 0; t < 4; ++t) {
    int idx = tid + t * 256;
    float s = red[0][idx] + red[1][idx] + red[2][idx] + red[3][idx];
    proj[(size_t)(row0 + (idx >> 5)) * 2080 + (idx & 31)] = f2bf(s);
  }
}

// y = (softplus(delta)*xc*bc + D*xc) * silu(z); in-place over xc. 8/thread.
__global__ void gate_kernel(const unsigned short* __restrict__ proj,  // [8192][2080]
                            const unsigned short* __restrict__ xz,    // z at col+2048
                            const float* __restrict__ Dw,             // [2048]
                            unsigned short* __restrict__ xc_y)        // [8192][2048]
{
  const int bl = blockIdx.x;
  const unsigned short* p = proj + (size_t)bl * 2080;
  u16x8 pb0 = *reinterpret_cast<const u16x8*>(p);
  u16x8 pb1 = *reinterpret_cast<const u16x8*>(p + 8);
  u16x8 pc0 = *reinterpret_cast<const u16x8*>(p + 16);
  u16x8 pc1 = *reinterpret_cast<const u16x8*>(p + 24);
  float bc = 0.f;
#pragma unroll
  for (int s = 0; s < 8; ++s)
    bc += bf2f(pb0[s]) * bf2f(pc0[s]) + bf2f(pb1[s]) * bf2f(pc1[s]);

  const int c0 = threadIdx.x * 8;
  u16x8 dv  = *reinterpret_cast<const u16x8*>(p + 32 + c0);
  u16x8 xcv = *reinterpret_cast<const u16x8*>(xc_y + (size_t)bl * 2048 + c0);
  u16x8 zv  = *reinterpret_cast<const u16x8*>(xz + (size_t)bl * 4096 + 2048 + c0);
  float4 d0 = reinterpret_cast<const float4*>(Dw)[c0 / 4];
  float4 d1 = reinterpret_cast<const float4*>(Dw)[c0 / 4 + 1];
  const float* dd0 = reinterpret_cast<const float*>(&d0);
  const float* dd1 = reinterpret_cast<const float*>(&d1);

  u16x8 o;
#pragma unroll
  for (int j = 0; j < 8; ++j) {
    float d = bf2f(dv[j]);
    float delta = (d > 15.f) ? d : __logf(1.f + __expf(d));
    float xv = bf2f(xcv[j]);
    float z  = bf2f(zv[j]);
    float Dj = (j < 4) ? dd0[j] : dd1[j - 4];
    float y = delta * xv * bc + Dj * xv;
    y *= z / (1.f + __expf(-z));
    o[j] = f2bf(y);
  }
  *reinterpret_cast<u16x8*>(xc_y + (size_t)bl * 2048 + c0) = o;
}

extern "C" void kernel_launch(void* const* d_in, const int* in_sizes, int n_in,
                              void* d_out, int out_size, void* d_ws, size_t ws_size,
                              hipStream_t stream) {
  const float* x       = (const float*)d_in[0]; // [8192][1024]
  const float* W_in    = (const float*)d_in[1]; // [4096][1024]
  const float* conv_w  = (const float*)d_in[2]; // [2048][4]
  const float* conv_b  = (const float*)d_in[3]; // [2048]
  const float* W_xproj = (const float*)d_in[4]; // [2080][2048]
  const float* Dw      = (const float*)d_in[5]; // [2048]
  const float* W_out   = (const float*)d_in[6]; // [1024][2048]
  float* out = (float*)d_out;                   // [8192][1024] fp32

  // Workspace layout (bf16 buffers)
  unsigned short* xz_bf   = (unsigned short*)d_ws;                 // 8192*4096
  unsigned short* xc_bf   = xz_bf  + (size_t)8192 * 4096;          // 8192*2048
  unsigned short* proj_bf = xc_bf  + (size_t)8192 * 2048;          // 8192*2080
  unsigned short* xb_bf   = proj_bf + (size_t)8192 * 2080;         // 8192*1024 (reused for W_xproj)
  unsigned short* w_bf    = xb_bf  + (size_t)8192 * 1024;          // 4096*1024 (reused for W_out)

  // 1) convert x + W_in
  cvt_head<<<8192 + 4096, 256, 0, stream>>>(x, xb_bf, W_in, w_bf);
  // 2) xz = x @ W_in^T   (M=8192, N=4096, K=1024) — 512 blocks, chunk cols=8
  gemm256<<<512, 512, 0, stream>>>(xb_bf, w_bf, xz_bf, 1024, 1024, 1024, 4096, 3);
  // 3) conv+silu -> xc, W_xproj -> xb region, W_out -> w_bf region
  mid_fused<<<256 + 4160 + 2048, 256, 0, stream>>>(xz_bf, conv_w, conv_b, xc_bf,
                                                   W_xproj, xb_bf, W_out, w_bf);
  // 4a) proj[:,0:32] = xc @ W_xproj[0:32]^T (memory-bound strip)
  proj_strip<<<256, 256, 0, stream>>>(xc_bf, xb_bf, proj_bf);
  // 4b) proj[:,32:2080] = xc @ W_xproj[32:2080]^T (M=8192, N=2048, K=2048)
  //     256 blocks = exactly 1 CU-round, chunk cols=4
  gemm256<<<256, 512, 0, stream>>>(xc_bf, xb_bf + (size_t)32 * 2048, proj_bf + 32,
                                   2048, 2048, 2048, 2080, 2);
  // 5) gate -> y (in place over xc)
  gate_kernel<<<8192, 256, 0, stream>>>(proj_bf, xz_bf, Dw, xc_bf);
  // 6) out = y @ W_out^T  (M=8192, N=1024, K=2048), fp32 out — legacy 128^2 (512 blocks)
  gemm_bt<0, 1><<<dim3(64, 8), 256, 0, stream>>>(xc_bf, w_bf, out, 1024, 2048, 2048, 2048, 1024);
}

// Round 8
// 346.330 us; speedup vs baseline: 1.0264x; 1.0264x over previous
//
#include <hip/hip_runtime.h>
#include <hip/hip_bf16.h>
#include <cstdint>
#include <cmath>

typedef __bf16 bf16x8 __attribute__((ext_vector_type(8)));
typedef float  f32x4  __attribute__((ext_vector_type(4)));
typedef unsigned short u16x8 __attribute__((ext_vector_type(8)));

#define BT 128   // tile M and N (legacy 128^2 kernel, used for GEMM3)
#define BK 64    // tile K

__device__ __forceinline__ float bf2f(unsigned short h) {
  union { unsigned int u; float f; } v; v.u = ((unsigned int)h) << 16;
  return v.f;
}
__device__ __forceinline__ unsigned short f2bf(float x) {
  union { float f; unsigned int u; } v; v.f = x;
  unsigned int r = v.u + 0x7fffu + ((v.u >> 16) & 1u);  // RNE
  return (unsigned short)(r >> 16);
}

__device__ __forceinline__ void gld_lds16(const void* g, void* l) {
  __builtin_amdgcn_global_load_lds(
      (const __attribute__((address_space(1))) unsigned int*)g,
      (__attribute__((address_space(3))) unsigned int*)l,
      16, 0, 0);
}

__device__ __forceinline__ void cvt4(const float* __restrict__ in,
                                     unsigned short* __restrict__ out, int i) {
  float4 v = reinterpret_cast<const float4*>(in)[i];
  ushort4 o;
  o.x = f2bf(v.x); o.y = f2bf(v.y); o.z = f2bf(v.z); o.w = f2bf(v.w);
  reinterpret_cast<ushort4*>(out)[i] = o;
}

// Head: convert x (8192 blocks) and W_in (4096 blocks) in one launch.
__global__ void cvt_head(const float* __restrict__ x, unsigned short* __restrict__ xb,
                         const float* __restrict__ W_in, unsigned short* __restrict__ wb) {
  int b = blockIdx.x;
  if (b < 8192) cvt4(x, xb, b * 256 + threadIdx.x);
  else          cvt4(W_in, wb, (b - 8192) * 256 + threadIdx.x);
}

// Conv strip: thread owns 8 channels x 32 rows, 3-tap history in registers.
__device__ void conv_strip(const unsigned short* __restrict__ xz,
                           const float* __restrict__ conv_w,
                           const float* __restrict__ conv_b,
                           unsigned short* __restrict__ xc,
                           int strip, int tid) {
  const int bl0  = strip * 32;
  const int seq0 = bl0 & ~4095;      // sequence start (B=2, L=4096)
  const int c0   = tid * 8;
  float w[4][8], bb[8];
#pragma unroll
  for (int j = 0; j < 8; ++j) {
    float4 wr = reinterpret_cast<const float4*>(conv_w)[c0 + j];
    w[0][j] = wr.x; w[1][j] = wr.y; w[2][j] = wr.z; w[3][j] = wr.w;
    bb[j] = conv_b[c0 + j];
  }
  float win[3][8];
#pragma unroll
  for (int i = 0; i < 3; ++i) {
    int r = bl0 - 3 + i;
    if (r >= seq0) {
      u16x8 v = *reinterpret_cast<const u16x8*>(xz + (size_t)r * 4096 + c0);
#pragma unroll
      for (int j = 0; j < 8; ++j) win[i][j] = bf2f(v[j]);
    } else {
#pragma unroll
      for (int j = 0; j < 8; ++j) win[i][j] = 0.f;
    }
  }
  for (int i = 0; i < 32; ++i) {
    const int bl = bl0 + i;
    u16x8 v = *reinterpret_cast<const u16x8*>(xz + (size_t)bl * 4096 + c0);
    u16x8 o;
#pragma unroll
    for (int j = 0; j < 8; ++j) {
      float cur = bf2f(v[j]);
      float a = bb[j] + w[0][j] * win[0][j] + w[1][j] * win[1][j]
                      + w[2][j] * win[2][j] + w[3][j] * cur;
      o[j] = f2bf(a / (1.f + __expf(-a)));
      win[0][j] = win[1][j]; win[1][j] = win[2][j]; win[2][j] = cur;
    }
    *reinterpret_cast<u16x8*>(xc + (size_t)bl * 2048 + c0) = o;
  }
}

// Mid: conv_silu + W_xproj cvt + W_out cvt, one launch.
__global__ void mid_fused(const unsigned short* __restrict__ xz,
                          const float* __restrict__ conv_w,
                          const float* __restrict__ conv_b,
                          unsigned short* __restrict__ xc,
                          const float* __restrict__ W_xproj, unsigned short* __restrict__ wx_bf,
                          const float* __restrict__ W_out,   unsigned short* __restrict__ wo_bf) {
  int b = blockIdx.x;
  if (b < 256) { conv_strip(xz, conv_w, conv_b, xc, b, threadIdx.x); return; }
  b -= 256;
  if (b < 4160) { cvt4(W_xproj, wx_bf, b * 256 + threadIdx.x); return; }
  cvt4(W_out, wo_bf, (b - 4160) * 256 + threadIdx.x);
}

// ---------------------------------------------------------------------------
// Legacy 128^2 kernel (m97 structure) — kept for GEMM3 (N=1024: 512 blocks).
// ---------------------------------------------------------------------------
template <int GUARD_N, int OUT_F32>
__global__ __launch_bounds__(256, 2)
void gemm_bt(const unsigned short* __restrict__ A,
             const unsigned short* __restrict__ B,
             void* __restrict__ Cv,
             int N, int K, int ldA, int ldB, int ldC)
{
  __shared__ __align__(16) unsigned short sA[BT * BK];
  __shared__ __align__(16) unsigned short sB[BT * BK];

  const int tid  = threadIdx.x;
  const int lane = tid & 63;
  const int wave = tid >> 6;
  const int row0 = blockIdx.x * BT;
  const int col0 = blockIdx.y * BT;

  const int wrow = (wave & 1) * 64;
  const int wcol = (wave >> 1) * 64;
  const int l15  = lane & 15;
  const int q    = lane >> 4;

  f32x4 acc[4][4];
#pragma unroll
  for (int i = 0; i < 4; ++i)
#pragma unroll
    for (int j = 0; j < 4; ++j)
      acc[i][j] = (f32x4){0.f, 0.f, 0.f, 0.f};

  const int nk = K / BK;
  for (int kt = 0; kt < nk; ++kt) {
    const int k0 = kt * BK;
#pragma unroll
    for (int t = 0; t < 4; ++t) {
      int c  = t * 256 + tid;
      int r  = c >> 3;
      int g  = c & 7;
      int gs = (g ^ (r & 7)) * 8;
      gld_lds16(A + (size_t)(row0 + r) * ldA + k0 + gs, (void*)(sA + c * 8));
      int br = col0 + r;
      if (GUARD_N) br = (br < N) ? br : (N - 1);
      gld_lds16(B + (size_t)br * ldB + k0 + gs, (void*)(sB + c * 8));
    }
    __syncthreads();

#pragma unroll
    for (int kk = 0; kk < BK; kk += 32) {
      const int grb = kk >> 3;
      bf16x8 af[4], bfr[4];
#pragma unroll
      for (int i = 0; i < 4; ++i) {
        int ar = wrow + i * 16 + l15;
        af[i] = *reinterpret_cast<const bf16x8*>(
            sA + ar * BK + (((grb + q) ^ (ar & 7)) << 3));
        int br = wcol + i * 16 + l15;
        bfr[i] = *reinterpret_cast<const bf16x8*>(
            sB + br * BK + (((grb + q) ^ (br & 7)) << 3));
      }
#pragma unroll
      for (int i = 0; i < 4; ++i)
#pragma unroll
        for (int j = 0; j < 4; ++j)
          acc[i][j] = __builtin_amdgcn_mfma_f32_16x16x32_bf16(af[i], bfr[j], acc[i][j], 0, 0, 0);
    }
    __syncthreads();
  }

#pragma unroll
  for (int i = 0; i < 4; ++i) {
#pragma unroll
    for (int j = 0; j < 4; ++j) {
      int colw = col0 + wcol + j * 16 + l15;
      if (GUARD_N && colw >= N) continue;
#pragma unroll
      for (int r = 0; r < 4; ++r) {
        int roww = row0 + wrow + i * 16 + q * 4 + r;
        if (OUT_F32)
          ((float*)Cv)[(size_t)roww * ldC + colw] = acc[i][j][r];
        else
          ((unsigned short*)Cv)[(size_t)roww * ldC + colw] = f2bf(acc[i][j][r]);
      }
    }
  }
}

// ---------------------------------------------------------------------------
// 256x256 8-phase GEMM — R5-verified K-loop (8 barriers/K-tile, no spill)
// + chunked XCD swizzle + R7-verified conflict-free LDS epilogue.
// Schedule (per iter = 2 K-tiles; 2 gload_lds per phase, VMW(4) at ph4/ph8):
//   ph1: stage A-odd h0 | MFMA p0 + rdA(p1)
//   ph2: stage A-odd h1 | MFMA p1 + rdA(p2)
//   ph3: stage B-even h0| MFMA p2 + rdA(p3)
//   ph4: stage B-even h1| VMW(4) | MFMA p3 + rdB(odd) + rdA(odd p0)
//   (odd tile mirrored). Region safety + vmcnt ledger as verified in R2/R3/R5.
// ---------------------------------------------------------------------------
#define BARX() do { __builtin_amdgcn_sched_barrier(0); \
                    __builtin_amdgcn_s_barrier(); \
                    __builtin_amdgcn_sched_barrier(0); } while (0)
#define VMW(n) asm volatile("s_waitcnt vmcnt(" #n ")" ::: "memory")
#define LGKM0() asm volatile("s_waitcnt lgkmcnt(0)" ::: "memory")

#define STAGE_A(b, h, kt) do { \
  const unsigned short* _p = Ab + (size_t)((h) * 128) * ldA + (kt) * 64; \
  gld_lds16(_p,                     (void*)&sA[b][((h) * 128      + rr) * 64 + (g8 << 3)]); \
  gld_lds16(_p + (size_t)64 * ldA,  (void*)&sA[b][((h) * 128 + 64 + rr) * 64 + (g8 << 3)]); \
} while (0)

#define STAGE_B(b, h, kt) do { \
  const unsigned short* _p = Bb + (size_t)((h) * 128) * ldB + (kt) * 64; \
  gld_lds16(_p,                     (void*)&sB[b][((h) * 128      + rr) * 64 + (g8 << 3)]); \
  gld_lds16(_p + (size_t)64 * ldB,  (void*)&sB[b][((h) * 128 + 64 + rr) * 64 + (g8 << 3)]); \
} while (0)

#define RD_A_SET(dst, b, p) do { \
  dst[0][0] = *reinterpret_cast<const bf16x8*>(&sA[b][aOff + (2*(p)    ) * 1024 + kph0]); \
  dst[0][1] = *reinterpret_cast<const bf16x8*>(&sA[b][aOff + (2*(p)    ) * 1024 + kph1]); \
  dst[1][0] = *reinterpret_cast<const bf16x8*>(&sA[b][aOff + (2*(p) + 1) * 1024 + kph0]); \
  dst[1][1] = *reinterpret_cast<const bf16x8*>(&sA[b][aOff + (2*(p) + 1) * 1024 + kph1]); \
} while (0)

#define RD_B_SET(dst, b) do { \
  dst[0][0] = *reinterpret_cast<const bf16x8*>(&sB[b][bOff + 0 * 1024 + kph0]); \
  dst[0][1] = *reinterpret_cast<const bf16x8*>(&sB[b][bOff + 0 * 1024 + kph1]); \
  dst[1][0] = *reinterpret_cast<const bf16x8*>(&sB[b][bOff + 1 * 1024 + kph0]); \
  dst[1][1] = *reinterpret_cast<const bf16x8*>(&sB[b][bOff + 1 * 1024 + kph1]); \
  dst[2][0] = *reinterpret_cast<const bf16x8*>(&sB[b][bOff + 2 * 1024 + kph0]); \
  dst[2][1] = *reinterpret_cast<const bf16x8*>(&sB[b][bOff + 2 * 1024 + kph1]); \
  dst[3][0] = *reinterpret_cast<const bf16x8*>(&sB[b][bOff + 3 * 1024 + kph0]); \
  dst[3][1] = *reinterpret_cast<const bf16x8*>(&sB[b][bOff + 3 * 1024 + kph1]); \
} while (0)

#define MMA(i, j, k, Af, Bf) \
  acc[i][j] = __builtin_amdgcn_mfma_f32_16x16x32_bf16(Af[(i) & 1][k], Bf[j][k], acc[i][j], 0, 0, 0)

// 16 MFMA, dependency distance 8: all 8 accs at k-half 0, then k-half 1.
#define MFMA_PH(p, Af, Bf) do { \
  __builtin_amdgcn_s_setprio(1); \
  MMA(2*(p),   0, 0, Af, Bf); MMA(2*(p),   1, 0, Af, Bf); \
  MMA(2*(p),   2, 0, Af, Bf); MMA(2*(p),   3, 0, Af, Bf); \
  MMA(2*(p)+1, 0, 0, Af, Bf); MMA(2*(p)+1, 1, 0, Af, Bf); \
  MMA(2*(p)+1, 2, 0, Af, Bf); MMA(2*(p)+1, 3, 0, Af, Bf); \
  MMA(2*(p),   0, 1, Af, Bf); MMA(2*(p),   1, 1, Af, Bf); \
  MMA(2*(p),   2, 1, Af, Bf); MMA(2*(p),   3, 1, Af, Bf); \
  MMA(2*(p)+1, 0, 1, Af, Bf); MMA(2*(p)+1, 1, 1, Af, Bf); \
  MMA(2*(p)+1, 2, 1, Af, Bf); MMA(2*(p)+1, 3, 1, Af, Bf); \
  __builtin_amdgcn_s_setprio(0); \
} while (0)

__global__ __launch_bounds__(512, 2)
void gemm256(const unsigned short* __restrict__ A,
             const unsigned short* __restrict__ B,
             unsigned short* __restrict__ C,
             int K, int ldA, int ldB, int ldC, int ccsh)
{
  __shared__ __align__(16) unsigned short smem[4 * 256 * 64];  // 128 KiB
  unsigned short (*sA)[256 * 64] = (unsigned short (*)[256 * 64])smem;
  unsigned short (*sB)[256 * 64] = (unsigned short (*)[256 * 64])(smem + 2 * 256 * 64);

  const int tid  = threadIdx.x;
  const int lane = tid & 63;
  const int wave = tid >> 6;
  const int wm = wave >> 2;      // 0..1
  const int wn = wave & 3;       // 0..3
  const int l15 = lane & 15;
  const int q   = lane >> 4;

  // Chunked XCD swizzle: XCD x owns an R x CC chunk of output tiles;
  // XCD grid = 2 chunk-cols x 4 chunk-rows. Bijective for nwg%8==0.
  const int nwg = gridDim.x;
  const int wg  = blockIdx.x;
  const int x   = wg & 7;
  const int c   = wg >> 3;
  const int CC  = 1 << ccsh;
  const int R   = (nwg >> 3) >> ccsh;
  const int row0 = ((x >> 1) * R + (c >> ccsh)) * 256;
  const int col0 = ((x & 1) * CC + (c & (CC - 1))) * 256;

  // staging geometry: thread covers row rr (+64 per 2nd load), k-group g8;
  // LDS slot (r,g) holds global k-group g^(r&7) -> pre-swizzled global source
  const int rr  = tid >> 3;
  const int g8  = tid & 7;
  const int gsw = ((g8 ^ (rr & 7)) << 3);
  const unsigned short* Ab = A + (size_t)(row0 + rr) * ldA + gsw;
  const unsigned short* Bb = B + (size_t)(col0 + rr) * ldB + gsw;

  // ds-read geometry
  const int aOff = (wm * 128 + l15) * 64;
  const int bOff = (wn * 64  + l15) * 64;
  const int a7   = l15 & 7;
  const int kph0 = ((q       ^ a7) << 3);  // k-groups 0..3 (kk=0)
  const int kph1 = (((4 + q) ^ a7) << 3);  // k-groups 4..7 (kk=32)

  f32x4 acc[8][4];
#pragma unroll
  for (int i = 0; i < 8; ++i)
#pragma unroll
    for (int j = 0; j < 4; ++j)
      acc[i][j] = (f32x4){0.f, 0.f, 0.f, 0.f};

  bf16x8 afe[2][2], afo[2][2];   // A fragments, phase-parity double buffer
  bf16x8 bfe[4][2], bfo[4][2];   // B fragments, K-tile-parity double buffer

  const int nk = K >> 6;
  // Prologue: tile0 A+B into buf0, tile1 B into buf1 (12 loads); wait tile0,
  // then prime registers for even-tile phase 0.
  STAGE_A(0, 0, 0); STAGE_A(0, 1, 0);
  STAGE_B(0, 0, 0); STAGE_B(0, 1, 0);
  STAGE_B(1, 0, 1); STAGE_B(1, 1, 1);
  VMW(4);
  BARX();
  RD_B_SET(bfe, 0); RD_A_SET(afe, 0, 0);

  const int niter = K >> 7;
  for (int it = 0; it < niter; ++it) {
    const int kt1 = 2 * it + 1;
    int ktE = 2 * it + 2; if (ktE > nk - 1) ktE = nk - 1;  // clamped tail restage
    int ktO = 2 * it + 3; if (ktO > nk - 1) ktO = nk - 1;

    // ---- even K-tile (buf0, bfe) ----
    STAGE_A(1, 0, kt1);
    BARX();
    MFMA_PH(0, afe, bfe); RD_A_SET(afo, 0, 1);
    BARX();
    STAGE_A(1, 1, kt1);
    BARX();
    MFMA_PH(1, afo, bfe); RD_A_SET(afe, 0, 2);
    BARX();
    STAGE_B(0, 0, ktE);
    BARX();
    MFMA_PH(2, afe, bfe); RD_A_SET(afo, 0, 3);
    BARX();
    STAGE_B(0, 1, ktE);
    VMW(4);
    BARX();
    MFMA_PH(3, afo, bfe); RD_B_SET(bfo, 1); RD_A_SET(afe, 1, 0);
    BARX();

    // ---- odd K-tile (buf1, bfo) ----
    STAGE_A(0, 0, ktE);
    BARX();
    MFMA_PH(0, afe, bfo); RD_A_SET(afo, 1, 1);
    BARX();
    STAGE_A(0, 1, ktE);
    BARX();
    MFMA_PH(1, afo, bfo); RD_A_SET(afe, 1, 2);
    BARX();
    STAGE_B(1, 0, ktO);
    BARX();
    MFMA_PH(2, afe, bfo); RD_A_SET(afo, 1, 3);
    BARX();
    STAGE_B(1, 1, ktO);
    VMW(4);
    BARX();
    MFMA_PH(3, afo, bfo); RD_B_SET(bfe, 0); RD_A_SET(afe, 0, 0);
    BARX();
  }

  // ---- Epilogue: drain everything, stage C tile in LDS, coalesced store ----
  VMW(0);
  LGKM0();
  BARX();
  {
    unsigned short* cs = smem;  // 65536 ushorts = one 256x256 bf16 C tile
    // q-XOR on col bits 4-5: write banks = (j^q) groups -> all 32 banks/wave.
#pragma unroll
    for (int i = 0; i < 8; ++i) {
      const int row = wm * 128 + i * 16 + q * 4;
#pragma unroll
      for (int j = 0; j < 4; ++j) {
        const int col = (wn * 64 + j * 16 + l15) ^ (q << 4);
#pragma unroll
        for (int r = 0; r < 4; ++r)
          cs[(row + r) * 256 + col] = f2bf(acc[i][j][r]);
      }
    }
    LGKM0();   // ds_writes committed before signaling
    BARX();
#pragma unroll
    for (int s = 0; s < 16; ++s) {
      const int u   = s * 4096 + tid * 8;   // ushort index, 16B per thread
      const int row = u >> 8;
      const int col = u & 255;
      const int rcol = col ^ (((row >> 2) & 3) << 4);  // inverse of write XOR
      u16x8 v = *reinterpret_cast<const u16x8*>(&cs[row * 256 + rcol]);
      *reinterpret_cast<u16x8*>(C + (size_t)(row0 + row) * ldC + col0 + col) = v;
    }
  }
}

// ---------------------------------------------------------------------------
// proj strip: proj[:, 0:32] = xc @ W_xproj[0:32]^T. Memory-bound (reads xc
// once, 33.5 MB). Block = 32 rows, 4 waves split K=2048 into 512 each,
// fp32 LDS reduction, bf16 out. Grid 256 -> all CUs.
// ---------------------------------------------------------------------------
__global__ __launch_bounds__(256)
void proj_strip(const unsigned short* __restrict__ xc,   // [8192][2048]
                const unsigned short* __restrict__ wx,   // [2080][2048], rows 0..31
                unsigned short* __restrict__ proj)       // [8192][2080]
{
  __shared__ float red[4][32 * 32];
  const int tid  = threadIdx.x;
  const int lane = tid & 63;
  const int wave = tid >> 6;
  const int l15  = lane & 15;
  const int q    = lane >> 4;
  const int row0 = blockIdx.x * 32;

  f32x4 acc[2][2];
#pragma unroll
  for (int i = 0; i < 2; ++i)
#pragma unroll
    for (int j = 0; j < 2; ++j) acc[i][j] = (f32x4){0.f, 0.f, 0.f, 0.f};

  const int kbase = wave * 512;
#pragma unroll 4
  for (int kk = 0; kk < 512; kk += 32) {
    const int k = kbase + kk + q * 8;
    bf16x8 a0 = *reinterpret_cast<const bf16x8*>(&xc[(size_t)(row0 + l15) * 2048 + k]);
    bf16x8 a1 = *reinterpret_cast<const bf16x8*>(&xc[(size_t)(row0 + 16 + l15) * 2048 + k]);
    bf16x8 b0 = *reinterpret_cast<const bf16x8*>(&wx[(size_t)(l15) * 2048 + k]);
    bf16x8 b1 = *reinterpret_cast<const bf16x8*>(&wx[(size_t)(16 + l15) * 2048 + k]);
    acc[0][0] = __builtin_amdgcn_mfma_f32_16x16x32_bf16(a0, b0, acc[0][0], 0, 0, 0);
    acc[0][1] = __builtin_amdgcn_mfma_f32_16x16x32_bf16(a0, b1, acc[0][1], 0, 0, 0);
    acc[1][0] = __builtin_amdgcn_mfma_f32_16x16x32_bf16(a1, b0, acc[1][0], 0, 0, 0);
    acc[1][1] = __builtin_amdgcn_mfma_f32_16x16x32_bf16(a1, b1, acc[1][1], 0, 0, 0);
  }

#pragma unroll
  for (int i = 0; i < 2; ++i)
#pragma unroll
    for (int j = 0; j < 2; ++j)
#pragma unroll
      for (int r = 0; r < 4; ++r)
        red[wave][(i * 16 + q * 4 + r) * 32 + j * 16 + l15] = acc[i][j][r];
  __syncthreads();

#pragma unroll
  for (int t = 0; t < 4; ++t) {
    int idx = tid + t * 256;
    float s = red[0][idx] + red[1][idx] + red[2][idx] + red[3][idx];
    proj[(size_t)(row0 + (idx >> 5)) * 2080 + (idx & 31)] = f2bf(s);
  }
}

// y = (softplus(delta)*xc*bc + D*xc) * silu(z); in-place over xc. 8/thread.
__global__ void gate_kernel(const unsigned short* __restrict__ proj,  // [8192][2080]
                            const unsigned short* __restrict__ xz,    // z at col+2048
                            const float* __restrict__ Dw,             // [2048]
                            unsigned short* __restrict__ xc_y)        // [8192][2048]
{
  const int bl = blockIdx.x;
  const unsigned short* p = proj + (size_t)bl * 2080;
  u16x8 pb0 = *reinterpret_cast<const u16x8*>(p);
  u16x8 pb1 = *reinterpret_cast<const u16x8*>(p + 8);
  u16x8 pc0 = *reinterpret_cast<const u16x8*>(p + 16);
  u16x8 pc1 = *reinterpret_cast<const u16x8*>(p + 24);
  float bc = 0.f;
#pragma unroll
  for (int s = 0; s < 8; ++s)
    bc += bf2f(pb0[s]) * bf2f(pc0[s]) + bf2f(pb1[s]) * bf2f(pc1[s]);

  const int c0 = threadIdx.x * 8;
  u16x8 dv  = *reinterpret_cast<const u16x8*>(p + 32 + c0);
  u16x8 xcv = *reinterpret_cast<const u16x8*>(xc_y + (size_t)bl * 2048 + c0);
  u16x8 zv  = *reinterpret_cast<const u16x8*>(xz + (size_t)bl * 4096 + 2048 + c0);
  float4 d0 = reinterpret_cast<const float4*>(Dw)[c0 / 4];
  float4 d1 = reinterpret_cast<const float4*>(Dw)[c0 / 4 + 1];
  const float* dd0 = reinterpret_cast<const float*>(&d0);
  const float* dd1 = reinterpret_cast<const float*>(&d1);

  u16x8 o;
#pragma unroll
  for (int j = 0; j < 8; ++j) {
    float d = bf2f(dv[j]);
    float delta = (d > 15.f) ? d : __logf(1.f + __expf(d));
    float xv = bf2f(xcv[j]);
    float z  = bf2f(zv[j]);
    float Dj = (j < 4) ? dd0[j] : dd1[j - 4];
    float y = delta * xv * bc + Dj * xv;
    y *= z / (1.f + __expf(-z));
    o[j] = f2bf(y);
  }
  *reinterpret_cast<u16x8*>(xc_y + (size_t)bl * 2048 + c0) = o;
}

extern "C" void kernel_launch(void* const* d_in, const int* in_sizes, int n_in,
                              void* d_out, int out_size, void* d_ws, size_t ws_size,
                              hipStream_t stream) {
  const float* x       = (const float*)d_in[0]; // [8192][1024]
  const float* W_in    = (const float*)d_in[1]; // [4096][1024]
  const float* conv_w  = (const float*)d_in[2]; // [2048][4]
  const float* conv_b  = (const float*)d_in[3]; // [2048]
  const float* W_xproj = (const float*)d_in[4]; // [2080][2048]
  const float* Dw      = (const float*)d_in[5]; // [2048]
  const float* W_out   = (const float*)d_in[6]; // [1024][2048]
  float* out = (float*)d_out;                   // [8192][1024] fp32

  // Workspace layout (bf16 buffers)
  unsigned short* xz_bf   = (unsigned short*)d_ws;                 // 8192*4096
  unsigned short* xc_bf   = xz_bf  + (size_t)8192 * 4096;          // 8192*2048
  unsigned short* proj_bf = xc_bf  + (size_t)8192 * 2048;          // 8192*2080
  unsigned short* xb_bf   = proj_bf + (size_t)8192 * 2080;         // 8192*1024 (reused for W_xproj)
  unsigned short* w_bf    = xb_bf  + (size_t)8192 * 1024;          // 4096*1024 (reused for W_out)

  // 1) convert x + W_in
  cvt_head<<<8192 + 4096, 256, 0, stream>>>(x, xb_bf, W_in, w_bf);
  // 2) xz = x @ W_in^T   (M=8192, N=4096, K=1024) — 512 blocks, chunk cols=8
  gemm256<<<512, 512, 0, stream>>>(xb_bf, w_bf, xz_bf, 1024, 1024, 1024, 4096, 3);
  // 3) conv+silu -> xc, W_xproj -> xb region, W_out -> w_bf region
  mid_fused<<<256 + 4160 + 2048, 256, 0, stream>>>(xz_bf, conv_w, conv_b, xc_bf,
                                                   W_xproj, xb_bf, W_out, w_bf);
  // 4a) proj[:,0:32] = xc @ W_xproj[0:32]^T (memory-bound strip)
  proj_strip<<<256, 256, 0, stream>>>(xc_bf, xb_bf, proj_bf);
  // 4b) proj[:,32:2080] = xc @ W_xproj[32:2080]^T (M=8192, N=2048, K=2048)
  //     256 blocks = exactly 1 CU-round, chunk cols=4
  gemm256<<<256, 512, 0, stream>>>(xc_bf, xb_bf + (size_t)32 * 2048, proj_bf + 32,
                                   2048, 2048, 2048, 2080, 2);
  // 5) gate -> y (in place over xc)
  gate_kernel<<<8192, 256, 0, stream>>>(proj_bf, xz_bf, Dw, xc_bf);
  // 6) out = y @ W_out^T  (M=8192, N=1024, K=2048), fp32 out — legacy 128^2 (512 blocks)
  gemm_bt<0, 1><<<dim3(64, 8), 256, 0, stream>>>(xc_bf, w_bf, out, 1024, 2048, 2048, 2048, 1024);
}

// Round 9
// 338.915 us; speedup vs baseline: 1.0488x; 1.0219x over previous
//
#include <hip/hip_runtime.h>
#include <hip/hip_bf16.h>
#include <cstdint>
#include <cmath>

typedef __bf16 bf16x8 __attribute__((ext_vector_type(8)));
typedef float  f32x4  __attribute__((ext_vector_type(4)));
typedef unsigned short u16x8 __attribute__((ext_vector_type(8)));

#define BT 128   // tile M and N (legacy 128^2 kernel, used for GEMM3)
#define BK 64    // tile K

__device__ __forceinline__ float bf2f(unsigned short h) {
  union { unsigned int u; float f; } v; v.u = ((unsigned int)h) << 16;
  return v.f;
}
__device__ __forceinline__ unsigned short f2bf(float x) {
  union { float f; unsigned int u; } v; v.f = x;
  unsigned int r = v.u + 0x7fffu + ((v.u >> 16) & 1u);  // RNE
  return (unsigned short)(r >> 16);
}

__device__ __forceinline__ void gld_lds16(const void* g, void* l) {
  __builtin_amdgcn_global_load_lds(
      (const __attribute__((address_space(1))) unsigned int*)g,
      (__attribute__((address_space(3))) unsigned int*)l,
      16, 0, 0);
}

__device__ __forceinline__ void cvt4(const float* __restrict__ in,
                                     unsigned short* __restrict__ out, int i) {
  float4 v = reinterpret_cast<const float4*>(in)[i];
  ushort4 o;
  o.x = f2bf(v.x); o.y = f2bf(v.y); o.z = f2bf(v.z); o.w = f2bf(v.w);
  reinterpret_cast<ushort4*>(out)[i] = o;
}

// Head: convert x (8192 blocks) and W_in (4096 blocks) in one launch.
__global__ void cvt_head(const float* __restrict__ x, unsigned short* __restrict__ xb,
                         const float* __restrict__ W_in, unsigned short* __restrict__ wb) {
  int b = blockIdx.x;
  if (b < 8192) cvt4(x, xb, b * 256 + threadIdx.x);
  else          cvt4(W_in, wb, (b - 8192) * 256 + threadIdx.x);
}

// Conv strip: thread owns 8 channels x 32 rows, 3-tap history in registers.
__device__ void conv_strip(const unsigned short* __restrict__ xz,
                           const float* __restrict__ conv_w,
                           const float* __restrict__ conv_b,
                           unsigned short* __restrict__ xc,
                           int strip, int tid) {
  const int bl0  = strip * 32;
  const int seq0 = bl0 & ~4095;      // sequence start (B=2, L=4096)
  const int c0   = tid * 8;
  float w[4][8], bb[8];
#pragma unroll
  for (int j = 0; j < 8; ++j) {
    float4 wr = reinterpret_cast<const float4*>(conv_w)[c0 + j];
    w[0][j] = wr.x; w[1][j] = wr.y; w[2][j] = wr.z; w[3][j] = wr.w;
    bb[j] = conv_b[c0 + j];
  }
  float win[3][8];
#pragma unroll
  for (int i = 0; i < 3; ++i) {
    int r = bl0 - 3 + i;
    if (r >= seq0) {
      u16x8 v = *reinterpret_cast<const u16x8*>(xz + (size_t)r * 4096 + c0);
#pragma unroll
      for (int j = 0; j < 8; ++j) win[i][j] = bf2f(v[j]);
    } else {
#pragma unroll
      for (int j = 0; j < 8; ++j) win[i][j] = 0.f;
    }
  }
  for (int i = 0; i < 32; ++i) {
    const int bl = bl0 + i;
    u16x8 v = *reinterpret_cast<const u16x8*>(xz + (size_t)bl * 4096 + c0);
    u16x8 o;
#pragma unroll
    for (int j = 0; j < 8; ++j) {
      float cur = bf2f(v[j]);
      float a = bb[j] + w[0][j] * win[0][j] + w[1][j] * win[1][j]
                      + w[2][j] * win[2][j] + w[3][j] * cur;
      o[j] = f2bf(a / (1.f + __expf(-a)));
      win[0][j] = win[1][j]; win[1][j] = win[2][j]; win[2][j] = cur;
    }
    *reinterpret_cast<u16x8*>(xc + (size_t)bl * 2048 + c0) = o;
  }
}

// Mid: conv_silu + W_xproj cvt + W_out cvt, one launch.
__global__ void mid_fused(const unsigned short* __restrict__ xz,
                          const float* __restrict__ conv_w,
                          const float* __restrict__ conv_b,
                          unsigned short* __restrict__ xc,
                          const float* __restrict__ W_xproj, unsigned short* __restrict__ wx_bf,
                          const float* __restrict__ W_out,   unsigned short* __restrict__ wo_bf) {
  int b = blockIdx.x;
  if (b < 256) { conv_strip(xz, conv_w, conv_b, xc, b, threadIdx.x); return; }
  b -= 256;
  if (b < 4160) { cvt4(W_xproj, wx_bf, b * 256 + threadIdx.x); return; }
  cvt4(W_out, wo_bf, (b - 4160) * 256 + threadIdx.x);
}

// ---------------------------------------------------------------------------
// Legacy 128^2 kernel (m97 structure) — kept for GEMM3 (N=1024: 512 blocks).
// ---------------------------------------------------------------------------
template <int GUARD_N, int OUT_F32>
__global__ __launch_bounds__(256, 2)
void gemm_bt(const unsigned short* __restrict__ A,
             const unsigned short* __restrict__ B,
             void* __restrict__ Cv,
             int N, int K, int ldA, int ldB, int ldC)
{
  __shared__ __align__(16) unsigned short sA[BT * BK];
  __shared__ __align__(16) unsigned short sB[BT * BK];

  const int tid  = threadIdx.x;
  const int lane = tid & 63;
  const int wave = tid >> 6;
  const int row0 = blockIdx.x * BT;
  const int col0 = blockIdx.y * BT;

  const int wrow = (wave & 1) * 64;
  const int wcol = (wave >> 1) * 64;
  const int l15  = lane & 15;
  const int q    = lane >> 4;

  f32x4 acc[4][4];
#pragma unroll
  for (int i = 0; i < 4; ++i)
#pragma unroll
    for (int j = 0; j < 4; ++j)
      acc[i][j] = (f32x4){0.f, 0.f, 0.f, 0.f};

  const int nk = K / BK;
  for (int kt = 0; kt < nk; ++kt) {
    const int k0 = kt * BK;
#pragma unroll
    for (int t = 0; t < 4; ++t) {
      int c  = t * 256 + tid;
      int r  = c >> 3;
      int g  = c & 7;
      int gs = (g ^ (r & 7)) * 8;
      gld_lds16(A + (size_t)(row0 + r) * ldA + k0 + gs, (void*)(sA + c * 8));
      int br = col0 + r;
      if (GUARD_N) br = (br < N) ? br : (N - 1);
      gld_lds16(B + (size_t)br * ldB + k0 + gs, (void*)(sB + c * 8));
    }
    __syncthreads();

#pragma unroll
    for (int kk = 0; kk < BK; kk += 32) {
      const int grb = kk >> 3;
      bf16x8 af[4], bfr[4];
#pragma unroll
      for (int i = 0; i < 4; ++i) {
        int ar = wrow + i * 16 + l15;
        af[i] = *reinterpret_cast<const bf16x8*>(
            sA + ar * BK + (((grb + q) ^ (ar & 7)) << 3));
        int br = wcol + i * 16 + l15;
        bfr[i] = *reinterpret_cast<const bf16x8*>(
            sB + br * BK + (((grb + q) ^ (br & 7)) << 3));
      }
#pragma unroll
      for (int i = 0; i < 4; ++i)
#pragma unroll
        for (int j = 0; j < 4; ++j)
          acc[i][j] = __builtin_amdgcn_mfma_f32_16x16x32_bf16(af[i], bfr[j], acc[i][j], 0, 0, 0);
    }
    __syncthreads();
  }

#pragma unroll
  for (int i = 0; i < 4; ++i) {
#pragma unroll
    for (int j = 0; j < 4; ++j) {
      int colw = col0 + wcol + j * 16 + l15;
      if (GUARD_N && colw >= N) continue;
#pragma unroll
      for (int r = 0; r < 4; ++r) {
        int roww = row0 + wrow + i * 16 + q * 4 + r;
        if (OUT_F32)
          ((float*)Cv)[(size_t)roww * ldC + colw] = acc[i][j][r];
        else
          ((unsigned short*)Cv)[(size_t)roww * ldC + colw] = f2bf(acc[i][j][r]);
      }
    }
  }
}

// ---------------------------------------------------------------------------
// 256x256 8-phase GEMM — R5/R8-verified K-loop (8 barriers/K-tile, no spill)
// + chunked XCD swizzle + conflict-free LDS epilogue.
// EPI=0: plain bf16 C store. EPI=1 (GEMM2): fused gate epilogue —
//   y[r][c] = (softplus(p)*xc*bc[r] + D[c]*xc) * silu(z), p = this GEMM's
//   output, xc = A operand (re-read, ld 2048), z = XZ[r][2048+c], written to
//   a SEPARATE y buffer (no race with other blocks' A reads).
// ---------------------------------------------------------------------------
#define BARX() do { __builtin_amdgcn_sched_barrier(0); \
                    __builtin_amdgcn_s_barrier(); \
                    __builtin_amdgcn_sched_barrier(0); } while (0)
#define VMW(n) asm volatile("s_waitcnt vmcnt(" #n ")" ::: "memory")
#define LGKM0() asm volatile("s_waitcnt lgkmcnt(0)" ::: "memory")

#define STAGE_A(b, h, kt) do { \
  const unsigned short* _p = Ab + (size_t)((h) * 128) * ldA + (kt) * 64; \
  gld_lds16(_p,                     (void*)&sA[b][((h) * 128      + rr) * 64 + (g8 << 3)]); \
  gld_lds16(_p + (size_t)64 * ldA,  (void*)&sA[b][((h) * 128 + 64 + rr) * 64 + (g8 << 3)]); \
} while (0)

#define STAGE_B(b, h, kt) do { \
  const unsigned short* _p = Bb + (size_t)((h) * 128) * ldB + (kt) * 64; \
  gld_lds16(_p,                     (void*)&sB[b][((h) * 128      + rr) * 64 + (g8 << 3)]); \
  gld_lds16(_p + (size_t)64 * ldB,  (void*)&sB[b][((h) * 128 + 64 + rr) * 64 + (g8 << 3)]); \
} while (0)

#define RD_A_SET(dst, b, p) do { \
  dst[0][0] = *reinterpret_cast<const bf16x8*>(&sA[b][aOff + (2*(p)    ) * 1024 + kph0]); \
  dst[0][1] = *reinterpret_cast<const bf16x8*>(&sA[b][aOff + (2*(p)    ) * 1024 + kph1]); \
  dst[1][0] = *reinterpret_cast<const bf16x8*>(&sA[b][aOff + (2*(p) + 1) * 1024 + kph0]); \
  dst[1][1] = *reinterpret_cast<const bf16x8*>(&sA[b][aOff + (2*(p) + 1) * 1024 + kph1]); \
} while (0)

#define RD_B_SET(dst, b) do { \
  dst[0][0] = *reinterpret_cast<const bf16x8*>(&sB[b][bOff + 0 * 1024 + kph0]); \
  dst[0][1] = *reinterpret_cast<const bf16x8*>(&sB[b][bOff + 0 * 1024 + kph1]); \
  dst[1][0] = *reinterpret_cast<const bf16x8*>(&sB[b][bOff + 1 * 1024 + kph0]); \
  dst[1][1] = *reinterpret_cast<const bf16x8*>(&sB[b][bOff + 1 * 1024 + kph1]); \
  dst[2][0] = *reinterpret_cast<const bf16x8*>(&sB[b][bOff + 2 * 1024 + kph0]); \
  dst[2][1] = *reinterpret_cast<const bf16x8*>(&sB[b][bOff + 2 * 1024 + kph1]); \
  dst[3][0] = *reinterpret_cast<const bf16x8*>(&sB[b][bOff + 3 * 1024 + kph0]); \
  dst[3][1] = *reinterpret_cast<const bf16x8*>(&sB[b][bOff + 3 * 1024 + kph1]); \
} while (0)

#define MMA(i, j, k, Af, Bf) \
  acc[i][j] = __builtin_amdgcn_mfma_f32_16x16x32_bf16(Af[(i) & 1][k], Bf[j][k], acc[i][j], 0, 0, 0)

// 16 MFMA, dependency distance 8: all 8 accs at k-half 0, then k-half 1.
#define MFMA_PH(p, Af, Bf) do { \
  __builtin_amdgcn_s_setprio(1); \
  MMA(2*(p),   0, 0, Af, Bf); MMA(2*(p),   1, 0, Af, Bf); \
  MMA(2*(p),   2, 0, Af, Bf); MMA(2*(p),   3, 0, Af, Bf); \
  MMA(2*(p)+1, 0, 0, Af, Bf); MMA(2*(p)+1, 1, 0, Af, Bf); \
  MMA(2*(p)+1, 2, 0, Af, Bf); MMA(2*(p)+1, 3, 0, Af, Bf); \
  MMA(2*(p),   0, 1, Af, Bf); MMA(2*(p),   1, 1, Af, Bf); \
  MMA(2*(p),   2, 1, Af, Bf); MMA(2*(p),   3, 1, Af, Bf); \
  MMA(2*(p)+1, 0, 1, Af, Bf); MMA(2*(p)+1, 1, 1, Af, Bf); \
  MMA(2*(p)+1, 2, 1, Af, Bf); MMA(2*(p)+1, 3, 1, Af, Bf); \
  __builtin_amdgcn_s_setprio(0); \
} while (0)

template <int EPI>
__global__ __launch_bounds__(512, 2)
void gemm256(const unsigned short* __restrict__ A,
             const unsigned short* __restrict__ B,
             unsigned short* __restrict__ C,
             int K, int ldA, int ldB, int ldC, int ccsh,
             const unsigned short* __restrict__ XZ,  // EPI=1: z at col 2048+
             const float* __restrict__ Dw,           // EPI=1: D[2048]
             const float* __restrict__ BC)           // EPI=1: bc[8192]
{
  __shared__ __align__(16) unsigned short smem[4 * 256 * 64];  // 128 KiB
  unsigned short (*sA)[256 * 64] = (unsigned short (*)[256 * 64])smem;
  unsigned short (*sB)[256 * 64] = (unsigned short (*)[256 * 64])(smem + 2 * 256 * 64);

  const int tid  = threadIdx.x;
  const int lane = tid & 63;
  const int wave = tid >> 6;
  const int wm = wave >> 2;      // 0..1
  const int wn = wave & 3;       // 0..3
  const int l15 = lane & 15;
  const int q   = lane >> 4;

  // Chunked XCD swizzle: XCD x owns an R x CC chunk of output tiles;
  // XCD grid = 2 chunk-cols x 4 chunk-rows. Bijective for nwg%8==0.
  const int nwg = gridDim.x;
  const int wg  = blockIdx.x;
  const int x   = wg & 7;
  const int c   = wg >> 3;
  const int CC  = 1 << ccsh;
  const int R   = (nwg >> 3) >> ccsh;
  const int row0 = ((x >> 1) * R + (c >> ccsh)) * 256;
  const int col0 = ((x & 1) * CC + (c & (CC - 1))) * 256;

  // staging geometry: thread covers row rr (+64 per 2nd load), k-group g8;
  // LDS slot (r,g) holds global k-group g^(r&7) -> pre-swizzled global source
  const int rr  = tid >> 3;
  const int g8  = tid & 7;
  const int gsw = ((g8 ^ (rr & 7)) << 3);
  const unsigned short* Ab = A + (size_t)(row0 + rr) * ldA + gsw;
  const unsigned short* Bb = B + (size_t)(col0 + rr) * ldB + gsw;

  // ds-read geometry
  const int aOff = (wm * 128 + l15) * 64;
  const int bOff = (wn * 64  + l15) * 64;
  const int a7   = l15 & 7;
  const int kph0 = ((q       ^ a7) << 3);  // k-groups 0..3 (kk=0)
  const int kph1 = (((4 + q) ^ a7) << 3);  // k-groups 4..7 (kk=32)

  f32x4 acc[8][4];
#pragma unroll
  for (int i = 0; i < 8; ++i)
#pragma unroll
    for (int j = 0; j < 4; ++j)
      acc[i][j] = (f32x4){0.f, 0.f, 0.f, 0.f};

  bf16x8 afe[2][2], afo[2][2];   // A fragments, phase-parity double buffer
  bf16x8 bfe[4][2], bfo[4][2];   // B fragments, K-tile-parity double buffer

  const int nk = K >> 6;
  // Prologue: tile0 A+B into buf0, tile1 B into buf1 (12 loads); wait tile0,
  // then prime registers for even-tile phase 0.
  STAGE_A(0, 0, 0); STAGE_A(0, 1, 0);
  STAGE_B(0, 0, 0); STAGE_B(0, 1, 0);
  STAGE_B(1, 0, 1); STAGE_B(1, 1, 1);
  VMW(4);
  BARX();
  RD_B_SET(bfe, 0); RD_A_SET(afe, 0, 0);

  const int niter = K >> 7;
  for (int it = 0; it < niter; ++it) {
    const int kt1 = 2 * it + 1;
    int ktE = 2 * it + 2; if (ktE > nk - 1) ktE = nk - 1;  // clamped tail restage
    int ktO = 2 * it + 3; if (ktO > nk - 1) ktO = nk - 1;

    // ---- even K-tile (buf0, bfe) ----
    STAGE_A(1, 0, kt1);
    BARX();
    MFMA_PH(0, afe, bfe); RD_A_SET(afo, 0, 1);
    BARX();
    STAGE_A(1, 1, kt1);
    BARX();
    MFMA_PH(1, afo, bfe); RD_A_SET(afe, 0, 2);
    BARX();
    STAGE_B(0, 0, ktE);
    BARX();
    MFMA_PH(2, afe, bfe); RD_A_SET(afo, 0, 3);
    BARX();
    STAGE_B(0, 1, ktE);
    VMW(4);
    BARX();
    MFMA_PH(3, afo, bfe); RD_B_SET(bfo, 1); RD_A_SET(afe, 1, 0);
    BARX();

    // ---- odd K-tile (buf1, bfo) ----
    STAGE_A(0, 0, ktE);
    BARX();
    MFMA_PH(0, afe, bfo); RD_A_SET(afo, 1, 1);
    BARX();
    STAGE_A(0, 1, ktE);
    BARX();
    MFMA_PH(1, afo, bfo); RD_A_SET(afe, 1, 2);
    BARX();
    STAGE_B(1, 0, ktO);
    BARX();
    MFMA_PH(2, afe, bfo); RD_A_SET(afo, 1, 3);
    BARX();
    STAGE_B(1, 1, ktO);
    VMW(4);
    BARX();
    MFMA_PH(3, afo, bfo); RD_B_SET(bfe, 0); RD_A_SET(afe, 0, 0);
    BARX();
  }

  // ---- Epilogue: drain, stage C tile in LDS (q-XOR, conflict-free), then
  //      coalesced store (EPI=0) or fused gate + y store (EPI=1). ----
  VMW(0);
  LGKM0();
  BARX();
  {
    unsigned short* cs = smem;  // 65536 ushorts = one 256x256 bf16 C tile
#pragma unroll
    for (int i = 0; i < 8; ++i) {
      const int row = wm * 128 + i * 16 + q * 4;
#pragma unroll
      for (int j = 0; j < 4; ++j) {
        const int col = (wn * 64 + j * 16 + l15) ^ (q << 4);
#pragma unroll
        for (int r = 0; r < 4; ++r)
          cs[(row + r) * 256 + col] = f2bf(acc[i][j][r]);
      }
    }
    LGKM0();   // ds_writes committed before signaling
    BARX();

    const int colf   = (tid * 8) & 255;   // fixed col-chunk per thread
    const int rowofs = tid >> 5;          // 0..15

    if (EPI == 0) {
#pragma unroll
      for (int s = 0; s < 16; ++s) {
        const int row  = s * 16 + rowofs;
        const int rcol = colf ^ (((row >> 2) & 3) << 4);  // inverse write XOR
        u16x8 v = *reinterpret_cast<const u16x8*>(&cs[row * 256 + rcol]);
        *reinterpret_cast<u16x8*>(C + (size_t)(row0 + row) * ldC + col0 + colf) = v;
      }
    } else {
      // Fused gate: y = (softplus(p)*xc*bc + D*xc) * silu(z)
      float dj[8];
      {
        float4 d0 = reinterpret_cast<const float4*>(Dw)[(col0 + colf) >> 2];
        float4 d1 = reinterpret_cast<const float4*>(Dw)[((col0 + colf) >> 2) + 1];
        dj[0] = d0.x; dj[1] = d0.y; dj[2] = d0.z; dj[3] = d0.w;
        dj[4] = d1.x; dj[5] = d1.y; dj[6] = d1.z; dj[7] = d1.w;
      }
#pragma unroll
      for (int s = 0; s < 16; ++s) {
        const int row  = s * 16 + rowofs;
        const int rcol = colf ^ (((row >> 2) & 3) << 4);
        const size_t gr = (size_t)(row0 + row);
        u16x8 pv  = *reinterpret_cast<const u16x8*>(&cs[row * 256 + rcol]);
        u16x8 xcv = *reinterpret_cast<const u16x8*>(A + gr * ldA + col0 + colf);
        u16x8 zv  = *reinterpret_cast<const u16x8*>(XZ + gr * 4096 + 2048 + col0 + colf);
        const float bcr = BC[gr];
        u16x8 o;
#pragma unroll
        for (int j = 0; j < 8; ++j) {
          float p  = bf2f(pv[j]);
          float delta = (p > 15.f) ? p : __logf(1.f + __expf(p));
          float xv = bf2f(xcv[j]);
          float zz = bf2f(zv[j]);
          float y  = delta * xv * bcr + dj[j] * xv;
          y *= zz / (1.f + __expf(-zz));
          o[j] = f2bf(y);
        }
        *reinterpret_cast<u16x8*>(C + gr * ldC + col0 + colf) = o;
      }
    }
  }
}

// ---------------------------------------------------------------------------
// proj strip -> bc: bc[row] = sum_s B[row][s]*C[row][s] where B,C are
// proj cols 0..15 / 16..31 (never materialized). Reads xc once (33.5 MB).
// Block = 32 rows, 4 waves split K=2048, padded-LDS reduction (33-stride
// avoids the 32-way same-bank pattern on per-row reads). Grid 256.
// ---------------------------------------------------------------------------
__global__ __launch_bounds__(256)
void proj_strip(const unsigned short* __restrict__ xc,   // [8192][2048]
                const unsigned short* __restrict__ wx,   // [2080][2048], rows 0..31
                float* __restrict__ bc)                  // [8192]
{
  __shared__ float red[4][32 * 33];
  const int tid  = threadIdx.x;
  const int lane = tid & 63;
  const int wave = tid >> 6;
  const int l15  = lane & 15;
  const int q    = lane >> 4;
  const int row0 = blockIdx.x * 32;

  f32x4 acc[2][2];
#pragma unroll
  for (int i = 0; i < 2; ++i)
#pragma unroll
    for (int j = 0; j < 2; ++j) acc[i][j] = (f32x4){0.f, 0.f, 0.f, 0.f};

  const int kbase = wave * 512;
#pragma unroll 4
  for (int kk = 0; kk < 512; kk += 32) {
    const int k = kbase + kk + q * 8;
    bf16x8 a0 = *reinterpret_cast<const bf16x8*>(&xc[(size_t)(row0 + l15) * 2048 + k]);
    bf16x8 a1 = *reinterpret_cast<const bf16x8*>(&xc[(size_t)(row0 + 16 + l15) * 2048 + k]);
    bf16x8 b0 = *reinterpret_cast<const bf16x8*>(&wx[(size_t)(l15) * 2048 + k]);
    bf16x8 b1 = *reinterpret_cast<const bf16x8*>(&wx[(size_t)(16 + l15) * 2048 + k]);
    acc[0][0] = __builtin_amdgcn_mfma_f32_16x16x32_bf16(a0, b0, acc[0][0], 0, 0, 0);
    acc[0][1] = __builtin_amdgcn_mfma_f32_16x16x32_bf16(a0, b1, acc[0][1], 0, 0, 0);
    acc[1][0] = __builtin_amdgcn_mfma_f32_16x16x32_bf16(a1, b0, acc[1][0], 0, 0, 0);
    acc[1][1] = __builtin_amdgcn_mfma_f32_16x16x32_bf16(a1, b1, acc[1][1], 0, 0, 0);
  }

  // C/D layout: col=lane&15, row=q*4+reg; i = row-half, j = col-half (B|C)
#pragma unroll
  for (int i = 0; i < 2; ++i)
#pragma unroll
    for (int j = 0; j < 2; ++j)
#pragma unroll
      for (int r = 0; r < 4; ++r)
        red[wave][(i * 16 + q * 4 + r) * 33 + j * 16 + l15] = acc[i][j][r];
  __syncthreads();

  if (tid < 32) {
    float s = 0.f;
#pragma unroll
    for (int cc = 0; cc < 16; ++cc) {
      const int ib = tid * 33 + cc;
      float b  = red[0][ib] + red[1][ib] + red[2][ib] + red[3][ib];
      float cv = red[0][ib + 16] + red[1][ib + 16] + red[2][ib + 16] + red[3][ib + 16];
      s += b * cv;
    }
    bc[row0 + tid] = s;
  }
}

extern "C" void kernel_launch(void* const* d_in, const int* in_sizes, int n_in,
                              void* d_out, int out_size, void* d_ws, size_t ws_size,
                              hipStream_t stream) {
  const float* x       = (const float*)d_in[0]; // [8192][1024]
  const float* W_in    = (const float*)d_in[1]; // [4096][1024]
  const float* conv_w  = (const float*)d_in[2]; // [2048][4]
  const float* conv_b  = (const float*)d_in[3]; // [2048]
  const float* W_xproj = (const float*)d_in[4]; // [2080][2048]
  const float* Dw      = (const float*)d_in[5]; // [2048]
  const float* W_out   = (const float*)d_in[6]; // [1024][2048]
  float* out = (float*)d_out;                   // [8192][1024] fp32

  // Workspace layout (bf16 buffers)
  unsigned short* xz_bf   = (unsigned short*)d_ws;                 // 8192*4096
  unsigned short* xc_bf   = xz_bf  + (size_t)8192 * 4096;          // 8192*2048
  unsigned short* y_bf    = xc_bf  + (size_t)8192 * 2048;          // 8192*2048 (old proj region)
  float*          bc_ws   = (float*)(y_bf + (size_t)8192 * 2048);  // 8192 fp32 (proj slack)
  unsigned short* xb_bf   = y_bf + (size_t)8192 * 2080;            // 8192*1024 (reused for W_xproj)
  unsigned short* w_bf    = xb_bf  + (size_t)8192 * 1024;          // 4096*1024 (reused for W_out)

  // 1) convert x + W_in
  cvt_head<<<8192 + 4096, 256, 0, stream>>>(x, xb_bf, W_in, w_bf);
  // 2) xz = x @ W_in^T   (M=8192, N=4096, K=1024) — 512 blocks, chunk cols=8
  gemm256<0><<<512, 512, 0, stream>>>(xb_bf, w_bf, xz_bf, 1024, 1024, 1024, 4096, 3,
                                      nullptr, nullptr, nullptr);
  // 3) conv+silu -> xc, W_xproj -> xb region, W_out -> w_bf region
  mid_fused<<<256 + 4160 + 2048, 256, 0, stream>>>(xz_bf, conv_w, conv_b, xc_bf,
                                                   W_xproj, xb_bf, W_out, w_bf);
  // 4a) bc[row] = proj[:,0:16] . proj[:,16:32] directly from xc @ W_xproj[0:32]^T
  proj_strip<<<256, 256, 0, stream>>>(xc_bf, xb_bf, bc_ws);
  // 4b) y = gate(xc @ W_xproj[32:2080]^T) fused epilogue (M=8192, N=2048, K=2048)
  //     256 blocks = exactly 1 CU-round, chunk cols=4; y -> y_bf (ld 2048)
  gemm256<1><<<256, 512, 0, stream>>>(xc_bf, xb_bf + (size_t)32 * 2048, y_bf,
                                      2048, 2048, 2048, 2048, 2,
                                      xz_bf, Dw, bc_ws);
  // 5) out = y @ W_out^T  (M=8192, N=1024, K=2048), fp32 out — legacy 128^2 (512 blocks)
  gemm_bt<0, 1><<<dim3(64, 8), 256, 0, stream>>>(y_bf, w_bf, out, 1024, 2048, 2048, 2048, 1024);
}

// Round 10
// 330.121 us; speedup vs baseline: 1.0768x; 1.0266x over previous
//
#include <hip/hip_runtime.h>
#include <hip/hip_bf16.h>
#include <cstdint>
#include <cmath>

typedef __bf16 bf16x8 __attribute__((ext_vector_type(8)));
typedef float  f32x4  __attribute__((ext_vector_type(4)));
typedef unsigned short u16x8 __attribute__((ext_vector_type(8)));

#define BT 128   // tile M and N (legacy 128^2 kernel, used for GEMM3)
#define BK 64    // tile K

__device__ __forceinline__ float bf2f(unsigned short h) {
  union { unsigned int u; float f; } v; v.u = ((unsigned int)h) << 16;
  return v.f;
}
__device__ __forceinline__ unsigned short f2bf(float x) {
  union { float f; unsigned int u; } v; v.f = x;
  unsigned int r = v.u + 0x7fffu + ((v.u >> 16) & 1u);  // RNE
  return (unsigned short)(r >> 16);
}

__device__ __forceinline__ void gld_lds16(const void* g, void* l) {
  __builtin_amdgcn_global_load_lds(
      (const __attribute__((address_space(1))) unsigned int*)g,
      (__attribute__((address_space(3))) unsigned int*)l,
      16, 0, 0);
}

__device__ __forceinline__ void cvt4(const float* __restrict__ in,
                                     unsigned short* __restrict__ out, int i) {
  float4 v = reinterpret_cast<const float4*>(in)[i];
  ushort4 o;
  o.x = f2bf(v.x); o.y = f2bf(v.y); o.z = f2bf(v.z); o.w = f2bf(v.w);
  reinterpret_cast<ushort4*>(out)[i] = o;
}

// Head: convert x (8192 blocks) and W_in (4096 blocks) in one launch.
__global__ void cvt_head(const float* __restrict__ x, unsigned short* __restrict__ xb,
                         const float* __restrict__ W_in, unsigned short* __restrict__ wb) {
  int b = blockIdx.x;
  if (b < 8192) cvt4(x, xb, b * 256 + threadIdx.x);
  else          cvt4(W_in, wb, (b - 8192) * 256 + threadIdx.x);
}

// Conv strip: thread owns 8 channels x 32 rows, 3-tap history in registers.
__device__ void conv_strip(const unsigned short* __restrict__ xz,
                           const float* __restrict__ conv_w,
                           const float* __restrict__ conv_b,
                           unsigned short* __restrict__ xc,
                           int strip, int tid) {
  const int bl0  = strip * 32;
  const int seq0 = bl0 & ~4095;      // sequence start (B=2, L=4096)
  const int c0   = tid * 8;
  float w[4][8], bb[8];
#pragma unroll
  for (int j = 0; j < 8; ++j) {
    float4 wr = reinterpret_cast<const float4*>(conv_w)[c0 + j];
    w[0][j] = wr.x; w[1][j] = wr.y; w[2][j] = wr.z; w[3][j] = wr.w;
    bb[j] = conv_b[c0 + j];
  }
  float win[3][8];
#pragma unroll
  for (int i = 0; i < 3; ++i) {
    int r = bl0 - 3 + i;
    if (r >= seq0) {
      u16x8 v = *reinterpret_cast<const u16x8*>(xz + (size_t)r * 4096 + c0);
#pragma unroll
      for (int j = 0; j < 8; ++j) win[i][j] = bf2f(v[j]);
    } else {
#pragma unroll
      for (int j = 0; j < 8; ++j) win[i][j] = 0.f;
    }
  }
  for (int i = 0; i < 32; ++i) {
    const int bl = bl0 + i;
    u16x8 v = *reinterpret_cast<const u16x8*>(xz + (size_t)bl * 4096 + c0);
    u16x8 o;
#pragma unroll
    for (int j = 0; j < 8; ++j) {
      float cur = bf2f(v[j]);
      float a = bb[j] + w[0][j] * win[0][j] + w[1][j] * win[1][j]
                      + w[2][j] * win[2][j] + w[3][j] * cur;
      o[j] = f2bf(a * __builtin_amdgcn_rcpf(1.f + __expf(-a)));
      win[0][j] = win[1][j]; win[1][j] = win[2][j]; win[2][j] = cur;
    }
    *reinterpret_cast<u16x8*>(xc + (size_t)bl * 2048 + c0) = o;
  }
}

// Mid: conv_silu + W_xproj cvt + W_out cvt, one launch.
__global__ void mid_fused(const unsigned short* __restrict__ xz,
                          const float* __restrict__ conv_w,
                          const float* __restrict__ conv_b,
                          unsigned short* __restrict__ xc,
                          const float* __restrict__ W_xproj, unsigned short* __restrict__ wx_bf,
                          const float* __restrict__ W_out,   unsigned short* __restrict__ wo_bf) {
  int b = blockIdx.x;
  if (b < 256) { conv_strip(xz, conv_w, conv_b, xc, b, threadIdx.x); return; }
  b -= 256;
  if (b < 4160) { cvt4(W_xproj, wx_bf, b * 256 + threadIdx.x); return; }
  cvt4(W_out, wo_bf, (b - 4160) * 256 + threadIdx.x);
}

// ---------------------------------------------------------------------------
// Legacy 128^2 kernel (m97 structure) — kept for GEMM3 (N=1024: 512 blocks).
// ---------------------------------------------------------------------------
template <int GUARD_N, int OUT_F32>
__global__ __launch_bounds__(256, 2)
void gemm_bt(const unsigned short* __restrict__ A,
             const unsigned short* __restrict__ B,
             void* __restrict__ Cv,
             int N, int K, int ldA, int ldB, int ldC)
{
  __shared__ __align__(16) unsigned short sA[BT * BK];
  __shared__ __align__(16) unsigned short sB[BT * BK];

  const int tid  = threadIdx.x;
  const int lane = tid & 63;
  const int wave = tid >> 6;
  const int row0 = blockIdx.x * BT;
  const int col0 = blockIdx.y * BT;

  const int wrow = (wave & 1) * 64;
  const int wcol = (wave >> 1) * 64;
  const int l15  = lane & 15;
  const int q    = lane >> 4;

  f32x4 acc[4][4];
#pragma unroll
  for (int i = 0; i < 4; ++i)
#pragma unroll
    for (int j = 0; j < 4; ++j)
      acc[i][j] = (f32x4){0.f, 0.f, 0.f, 0.f};

  const int nk = K / BK;
  for (int kt = 0; kt < nk; ++kt) {
    const int k0 = kt * BK;
#pragma unroll
    for (int t = 0; t < 4; ++t) {
      int c  = t * 256 + tid;
      int r  = c >> 3;
      int g  = c & 7;
      int gs = (g ^ (r & 7)) * 8;
      gld_lds16(A + (size_t)(row0 + r) * ldA + k0 + gs, (void*)(sA + c * 8));
      int br = col0 + r;
      if (GUARD_N) br = (br < N) ? br : (N - 1);
      gld_lds16(B + (size_t)br * ldB + k0 + gs, (void*)(sB + c * 8));
    }
    __syncthreads();

#pragma unroll
    for (int kk = 0; kk < BK; kk += 32) {
      const int grb = kk >> 3;
      bf16x8 af[4], bfr[4];
#pragma unroll
      for (int i = 0; i < 4; ++i) {
        int ar = wrow + i * 16 + l15;
        af[i] = *reinterpret_cast<const bf16x8*>(
            sA + ar * BK + (((grb + q) ^ (ar & 7)) << 3));
        int br = wcol + i * 16 + l15;
        bfr[i] = *reinterpret_cast<const bf16x8*>(
            sB + br * BK + (((grb + q) ^ (br & 7)) << 3));
      }
#pragma unroll
      for (int i = 0; i < 4; ++i)
#pragma unroll
        for (int j = 0; j < 4; ++j)
          acc[i][j] = __builtin_amdgcn_mfma_f32_16x16x32_bf16(af[i], bfr[j], acc[i][j], 0, 0, 0);
    }
    __syncthreads();
  }

#pragma unroll
  for (int i = 0; i < 4; ++i) {
#pragma unroll
    for (int j = 0; j < 4; ++j) {
      int colw = col0 + wcol + j * 16 + l15;
      if (GUARD_N && colw >= N) continue;
#pragma unroll
      for (int r = 0; r < 4; ++r) {
        int roww = row0 + wrow + i * 16 + q * 4 + r;
        if (OUT_F32)
          ((float*)Cv)[(size_t)roww * ldC + colw] = acc[i][j][r];
        else
          ((unsigned short*)Cv)[(size_t)roww * ldC + colw] = f2bf(acc[i][j][r]);
      }
    }
  }
}

// ---------------------------------------------------------------------------
// 256x256 8-phase GEMM — R5/R8-verified K-loop (8 barriers/K-tile, no spill)
// + chunked XCD swizzle + conflict-free LDS epilogue.
// EPI=0: plain bf16 C store. EPI=1 (GEMM2): fused gate epilogue, now
// latency-pipelined: first xc/z/bc batch + D row issued BEFORE the barrier
// (acc regs dead by then), and each iteration prefetches batch s+1 before
// consuming batch s. silu via v_rcp (error << bf16 ulp).
// ---------------------------------------------------------------------------
#define BARX() do { __builtin_amdgcn_sched_barrier(0); \
                    __builtin_amdgcn_s_barrier(); \
                    __builtin_amdgcn_sched_barrier(0); } while (0)
#define VMW(n) asm volatile("s_waitcnt vmcnt(" #n ")" ::: "memory")
#define LGKM0() asm volatile("s_waitcnt lgkmcnt(0)" ::: "memory")

#define STAGE_A(b, h, kt) do { \
  const unsigned short* _p = Ab + (size_t)((h) * 128) * ldA + (kt) * 64; \
  gld_lds16(_p,                     (void*)&sA[b][((h) * 128      + rr) * 64 + (g8 << 3)]); \
  gld_lds16(_p + (size_t)64 * ldA,  (void*)&sA[b][((h) * 128 + 64 + rr) * 64 + (g8 << 3)]); \
} while (0)

#define STAGE_B(b, h, kt) do { \
  const unsigned short* _p = Bb + (size_t)((h) * 128) * ldB + (kt) * 64; \
  gld_lds16(_p,                     (void*)&sB[b][((h) * 128      + rr) * 64 + (g8 << 3)]); \
  gld_lds16(_p + (size_t)64 * ldB,  (void*)&sB[b][((h) * 128 + 64 + rr) * 64 + (g8 << 3)]); \
} while (0)

#define RD_A_SET(dst, b, p) do { \
  dst[0][0] = *reinterpret_cast<const bf16x8*>(&sA[b][aOff + (2*(p)    ) * 1024 + kph0]); \
  dst[0][1] = *reinterpret_cast<const bf16x8*>(&sA[b][aOff + (2*(p)    ) * 1024 + kph1]); \
  dst[1][0] = *reinterpret_cast<const bf16x8*>(&sA[b][aOff + (2*(p) + 1) * 1024 + kph0]); \
  dst[1][1] = *reinterpret_cast<const bf16x8*>(&sA[b][aOff + (2*(p) + 1) * 1024 + kph1]); \
} while (0)

#define RD_B_SET(dst, b) do { \
  dst[0][0] = *reinterpret_cast<const bf16x8*>(&sB[b][bOff + 0 * 1024 + kph0]); \
  dst[0][1] = *reinterpret_cast<const bf16x8*>(&sB[b][bOff + 0 * 1024 + kph1]); \
  dst[1][0] = *reinterpret_cast<const bf16x8*>(&sB[b][bOff + 1 * 1024 + kph0]); \
  dst[1][1] = *reinterpret_cast<const bf16x8*>(&sB[b][bOff + 1 * 1024 + kph1]); \
  dst[2][0] = *reinterpret_cast<const bf16x8*>(&sB[b][bOff + 2 * 1024 + kph0]); \
  dst[2][1] = *reinterpret_cast<const bf16x8*>(&sB[b][bOff + 2 * 1024 + kph1]); \
  dst[3][0] = *reinterpret_cast<const bf16x8*>(&sB[b][bOff + 3 * 1024 + kph0]); \
  dst[3][1] = *reinterpret_cast<const bf16x8*>(&sB[b][bOff + 3 * 1024 + kph1]); \
} while (0)

#define MMA(i, j, k, Af, Bf) \
  acc[i][j] = __builtin_amdgcn_mfma_f32_16x16x32_bf16(Af[(i) & 1][k], Bf[j][k], acc[i][j], 0, 0, 0)

// 16 MFMA, dependency distance 8: all 8 accs at k-half 0, then k-half 1.
#define MFMA_PH(p, Af, Bf) do { \
  __builtin_amdgcn_s_setprio(1); \
  MMA(2*(p),   0, 0, Af, Bf); MMA(2*(p),   1, 0, Af, Bf); \
  MMA(2*(p),   2, 0, Af, Bf); MMA(2*(p),   3, 0, Af, Bf); \
  MMA(2*(p)+1, 0, 0, Af, Bf); MMA(2*(p)+1, 1, 0, Af, Bf); \
  MMA(2*(p)+1, 2, 0, Af, Bf); MMA(2*(p)+1, 3, 0, Af, Bf); \
  MMA(2*(p),   0, 1, Af, Bf); MMA(2*(p),   1, 1, Af, Bf); \
  MMA(2*(p),   2, 1, Af, Bf); MMA(2*(p),   3, 1, Af, Bf); \
  MMA(2*(p)+1, 0, 1, Af, Bf); MMA(2*(p)+1, 1, 1, Af, Bf); \
  MMA(2*(p)+1, 2, 1, Af, Bf); MMA(2*(p)+1, 3, 1, Af, Bf); \
  __builtin_amdgcn_s_setprio(0); \
} while (0)

template <int EPI>
__global__ __launch_bounds__(512, 2)
void gemm256(const unsigned short* __restrict__ A,
             const unsigned short* __restrict__ B,
             unsigned short* __restrict__ C,
             int K, int ldA, int ldB, int ldC, int ccsh,
             const unsigned short* __restrict__ XZ,  // EPI=1: z at col 2048+
             const float* __restrict__ Dw,           // EPI=1: D[2048]
             const float* __restrict__ BC)           // EPI=1: bc[8192]
{
  __shared__ __align__(16) unsigned short smem[4 * 256 * 64];  // 128 KiB
  unsigned short (*sA)[256 * 64] = (unsigned short (*)[256 * 64])smem;
  unsigned short (*sB)[256 * 64] = (unsigned short (*)[256 * 64])(smem + 2 * 256 * 64);

  const int tid  = threadIdx.x;
  const int lane = tid & 63;
  const int wave = tid >> 6;
  const int wm = wave >> 2;      // 0..1
  const int wn = wave & 3;       // 0..3
  const int l15 = lane & 15;
  const int q   = lane >> 4;

  // Chunked XCD swizzle: XCD x owns an R x CC chunk of output tiles;
  // XCD grid = 2 chunk-cols x 4 chunk-rows. Bijective for nwg%8==0.
  const int nwg = gridDim.x;
  const int wg  = blockIdx.x;
  const int x   = wg & 7;
  const int c   = wg >> 3;
  const int CC  = 1 << ccsh;
  const int R   = (nwg >> 3) >> ccsh;
  const int row0 = ((x >> 1) * R + (c >> ccsh)) * 256;
  const int col0 = ((x & 1) * CC + (c & (CC - 1))) * 256;

  // staging geometry: thread covers row rr (+64 per 2nd load), k-group g8;
  // LDS slot (r,g) holds global k-group g^(r&7) -> pre-swizzled global source
  const int rr  = tid >> 3;
  const int g8  = tid & 7;
  const int gsw = ((g8 ^ (rr & 7)) << 3);
  const unsigned short* Ab = A + (size_t)(row0 + rr) * ldA + gsw;
  const unsigned short* Bb = B + (size_t)(col0 + rr) * ldB + gsw;

  // ds-read geometry
  const int aOff = (wm * 128 + l15) * 64;
  const int bOff = (wn * 64  + l15) * 64;
  const int a7   = l15 & 7;
  const int kph0 = ((q       ^ a7) << 3);  // k-groups 0..3 (kk=0)
  const int kph1 = (((4 + q) ^ a7) << 3);  // k-groups 4..7 (kk=32)

  f32x4 acc[8][4];
#pragma unroll
  for (int i = 0; i < 8; ++i)
#pragma unroll
    for (int j = 0; j < 4; ++j)
      acc[i][j] = (f32x4){0.f, 0.f, 0.f, 0.f};

  bf16x8 afe[2][2], afo[2][2];   // A fragments, phase-parity double buffer
  bf16x8 bfe[4][2], bfo[4][2];   // B fragments, K-tile-parity double buffer

  const int nk = K >> 6;
  // Prologue: tile0 A+B into buf0, tile1 B into buf1 (12 loads); wait tile0,
  // then prime registers for even-tile phase 0.
  STAGE_A(0, 0, 0); STAGE_A(0, 1, 0);
  STAGE_B(0, 0, 0); STAGE_B(0, 1, 0);
  STAGE_B(1, 0, 1); STAGE_B(1, 1, 1);
  VMW(4);
  BARX();
  RD_B_SET(bfe, 0); RD_A_SET(afe, 0, 0);

  const int niter = K >> 7;
  for (int it = 0; it < niter; ++it) {
    const int kt1 = 2 * it + 1;
    int ktE = 2 * it + 2; if (ktE > nk - 1) ktE = nk - 1;  // clamped tail restage
    int ktO = 2 * it + 3; if (ktO > nk - 1) ktO = nk - 1;

    // ---- even K-tile (buf0, bfe) ----
    STAGE_A(1, 0, kt1);
    BARX();
    MFMA_PH(0, afe, bfe); RD_A_SET(afo, 0, 1);
    BARX();
    STAGE_A(1, 1, kt1);
    BARX();
    MFMA_PH(1, afo, bfe); RD_A_SET(afe, 0, 2);
    BARX();
    STAGE_B(0, 0, ktE);
    BARX();
    MFMA_PH(2, afe, bfe); RD_A_SET(afo, 0, 3);
    BARX();
    STAGE_B(0, 1, ktE);
    VMW(4);
    BARX();
    MFMA_PH(3, afo, bfe); RD_B_SET(bfo, 1); RD_A_SET(afe, 1, 0);
    BARX();

    // ---- odd K-tile (buf1, bfo) ----
    STAGE_A(0, 0, ktE);
    BARX();
    MFMA_PH(0, afe, bfo); RD_A_SET(afo, 1, 1);
    BARX();
    STAGE_A(0, 1, ktE);
    BARX();
    MFMA_PH(1, afo, bfo); RD_A_SET(afe, 1, 2);
    BARX();
    STAGE_B(1, 0, ktO);
    BARX();
    MFMA_PH(2, afe, bfo); RD_A_SET(afo, 1, 3);
    BARX();
    STAGE_B(1, 1, ktO);
    VMW(4);
    BARX();
    MFMA_PH(3, afo, bfo); RD_B_SET(bfe, 0); RD_A_SET(afe, 0, 0);
    BARX();
  }

  // ---- Epilogue: drain, stage C tile in LDS (q-XOR, conflict-free), then
  //      coalesced store (EPI=0) or fused gate + y store (EPI=1). ----
  VMW(0);
  LGKM0();
  BARX();
  {
    unsigned short* cs = smem;  // 65536 ushorts = one 256x256 bf16 C tile
#pragma unroll
    for (int i = 0; i < 8; ++i) {
      const int row = wm * 128 + i * 16 + q * 4;
#pragma unroll
      for (int j = 0; j < 4; ++j) {
        const int col = (wn * 64 + j * 16 + l15) ^ (q << 4);
#pragma unroll
        for (int r = 0; r < 4; ++r)
          cs[(row + r) * 256 + col] = f2bf(acc[i][j][r]);
      }
    }

    const int colf   = (tid * 8) & 255;   // fixed col-chunk per thread
    const int rowofs = tid >> 5;          // 0..15
    const int colX   = col0 + colf;

    if (EPI == 0) {
      LGKM0();   // ds_writes committed before signaling
      BARX();
#pragma unroll
      for (int s = 0; s < 16; ++s) {
        const int row  = s * 16 + rowofs;
        const int rcol = colf ^ (((row >> 2) & 3) << 4);  // inverse write XOR
        u16x8 v = *reinterpret_cast<const u16x8*>(&cs[row * 256 + rcol]);
        *reinterpret_cast<u16x8*>(C + (size_t)(row0 + row) * ldC + colX) = v;
      }
    } else {
      // Issue D row + first xc/z/bc batch BEFORE the barrier: acc is dead,
      // barrier latency covers the first HBM round trip.
      float dj[8];
      float4 d0 = reinterpret_cast<const float4*>(Dw)[colX >> 2];
      float4 d1 = reinterpret_cast<const float4*>(Dw)[(colX >> 2) + 1];
      dj[0] = d0.x; dj[1] = d0.y; dj[2] = d0.z; dj[3] = d0.w;
      dj[4] = d1.x; dj[5] = d1.y; dj[6] = d1.z; dj[7] = d1.w;
      const size_t g0 = (size_t)(row0 + rowofs);
      u16x8 xc_c = *reinterpret_cast<const u16x8*>(A + g0 * ldA + colX);
      u16x8 zv_c = *reinterpret_cast<const u16x8*>(XZ + g0 * 4096 + 2048 + colX);
      float bc_c = BC[g0];

      LGKM0();   // ds_writes committed before signaling
      BARX();

      // 2-deep pipeline: prefetch batch s+1, consume batch s.
#pragma unroll
      for (int s = 0; s < 16; ++s) {
        u16x8 xc_n, zv_n; float bc_n;
        if (s < 15) {
          const size_t gn = (size_t)(row0 + (s + 1) * 16 + rowofs);
          xc_n = *reinterpret_cast<const u16x8*>(A + gn * ldA + colX);
          zv_n = *reinterpret_cast<const u16x8*>(XZ + gn * 4096 + 2048 + colX);
          bc_n = BC[gn];
        }
        const int row  = s * 16 + rowofs;
        const int rcol = colf ^ (((row >> 2) & 3) << 4);
        const size_t gr = (size_t)(row0 + row);
        u16x8 pv = *reinterpret_cast<const u16x8*>(&cs[row * 256 + rcol]);
        u16x8 o;
#pragma unroll
        for (int j = 0; j < 8; ++j) {
          float p  = bf2f(pv[j]);
          float delta = (p > 15.f) ? p : __logf(1.f + __expf(p));
          float xv = bf2f(xc_c[j]);
          float zz = bf2f(zv_c[j]);
          float y  = delta * xv * bc_c + dj[j] * xv;
          y *= zz * __builtin_amdgcn_rcpf(1.f + __expf(-zz));
          o[j] = f2bf(y);
        }
        *reinterpret_cast<u16x8*>(C + gr * ldC + colX) = o;
        if (s < 15) { xc_c = xc_n; zv_c = zv_n; bc_c = bc_n; }
      }
    }
  }
}

// ---------------------------------------------------------------------------
// proj strip -> bc: bc[row] = sum_s B[row][s]*C[row][s] where B,C are
// proj cols 0..15 / 16..31 (never materialized). Reads xc once (33.5 MB).
// Block = 32 rows, 4 waves split K=2048, padded-LDS reduction. Grid 256.
// ---------------------------------------------------------------------------
__global__ __launch_bounds__(256)
void proj_strip(const unsigned short* __restrict__ xc,   // [8192][2048]
                const unsigned short* __restrict__ wx,   // [2080][2048], rows 0..31
                float* __restrict__ bc)                  // [8192]
{
  __shared__ float red[4][32 * 33];
  const int tid  = threadIdx.x;
  const int lane = tid & 63;
  const int wave = tid >> 6;
  const int l15  = lane & 15;
  const int q    = lane >> 4;
  const int row0 = blockIdx.x * 32;

  f32x4 acc[2][2];
#pragma unroll
  for (int i = 0; i < 2; ++i)
#pragma unroll
    for (int j = 0; j < 2; ++j) acc[i][j] = (f32x4){0.f, 0.f, 0.f, 0.f};

  const int kbase = wave * 512;
#pragma unroll 4
  for (int kk = 0; kk < 512; kk += 32) {
    const int k = kbase + kk + q * 8;
    bf16x8 a0 = *reinterpret_cast<const bf16x8*>(&xc[(size_t)(row0 + l15) * 2048 + k]);
    bf16x8 a1 = *reinterpret_cast<const bf16x8*>(&xc[(size_t)(row0 + 16 + l15) * 2048 + k]);
    bf16x8 b0 = *reinterpret_cast<const bf16x8*>(&wx[(size_t)(l15) * 2048 + k]);
    bf16x8 b1 = *reinterpret_cast<const bf16x8*>(&wx[(size_t)(16 + l15) * 2048 + k]);
    acc[0][0] = __builtin_amdgcn_mfma_f32_16x16x32_bf16(a0, b0, acc[0][0], 0, 0, 0);
    acc[0][1] = __builtin_amdgcn_mfma_f32_16x16x32_bf16(a0, b1, acc[0][1], 0, 0, 0);
    acc[1][0] = __builtin_amdgcn_mfma_f32_16x16x32_bf16(a1, b0, acc[1][0], 0, 0, 0);
    acc[1][1] = __builtin_amdgcn_mfma_f32_16x16x32_bf16(a1, b1, acc[1][1], 0, 0, 0);
  }

  // C/D layout: col=lane&15, row=q*4+reg; i = row-half, j = col-half (B|C)
#pragma unroll
  for (int i = 0; i < 2; ++i)
#pragma unroll
    for (int j = 0; j < 2; ++j)
#pragma unroll
      for (int r = 0; r < 4; ++r)
        red[wave][(i * 16 + q * 4 + r) * 33 + j * 16 + l15] = acc[i][j][r];
  __syncthreads();

  if (tid < 32) {
    float s = 0.f;
#pragma unroll
    for (int cc = 0; cc < 16; ++cc) {
      const int ib = tid * 33 + cc;
      float b  = red[0][ib] + red[1][ib] + red[2][ib] + red[3][ib];
      float cv = red[0][ib + 16] + red[1][ib + 16] + red[2][ib + 16] + red[3][ib + 16];
      s += b * cv;
    }
    bc[row0 + tid] = s;
  }
}

extern "C" void kernel_launch(void* const* d_in, const int* in_sizes, int n_in,
                              void* d_out, int out_size, void* d_ws, size_t ws_size,
                              hipStream_t stream) {
  const float* x       = (const float*)d_in[0]; // [8192][1024]
  const float* W_in    = (const float*)d_in[1]; // [4096][1024]
  const float* conv_w  = (const float*)d_in[2]; // [2048][4]
  const float* conv_b  = (const float*)d_in[3]; // [2048]
  const float* W_xproj = (const float*)d_in[4]; // [2080][2048]
  const float* Dw      = (const float*)d_in[5]; // [2048]
  const float* W_out   = (const float*)d_in[6]; // [1024][2048]
  float* out = (float*)d_out;                   // [8192][1024] fp32

  // Workspace layout (bf16 buffers)
  unsigned short* xz_bf   = (unsigned short*)d_ws;                 // 8192*4096
  unsigned short* xc_bf   = xz_bf  + (size_t)8192 * 4096;          // 8192*2048
  unsigned short* y_bf    = xc_bf  + (size_t)8192 * 2048;          // 8192*2048 (old proj region)
  float*          bc_ws   = (float*)(y_bf + (size_t)8192 * 2048);  // 8192 fp32 (proj slack)
  unsigned short* xb_bf   = y_bf + (size_t)8192 * 2080;            // 8192*1024 (reused for W_xproj)
  unsigned short* w_bf    = xb_bf  + (size_t)8192 * 1024;          // 4096*1024 (reused for W_out)

  // 1) convert x + W_in
  cvt_head<<<8192 + 4096, 256, 0, stream>>>(x, xb_bf, W_in, w_bf);
  // 2) xz = x @ W_in^T   (M=8192, N=4096, K=1024) — 512 blocks, chunk cols=8
  gemm256<0><<<512, 512, 0, stream>>>(xb_bf, w_bf, xz_bf, 1024, 1024, 1024, 4096, 3,
                                      nullptr, nullptr, nullptr);
  // 3) conv+silu -> xc, W_xproj -> xb region, W_out -> w_bf region
  mid_fused<<<256 + 4160 + 2048, 256, 0, stream>>>(xz_bf, conv_w, conv_b, xc_bf,
                                                   W_xproj, xb_bf, W_out, w_bf);
  // 4a) bc[row] = proj[:,0:16] . proj[:,16:32] directly from xc @ W_xproj[0:32]^T
  proj_strip<<<256, 256, 0, stream>>>(xc_bf, xb_bf, bc_ws);
  // 4b) y = gate(xc @ W_xproj[32:2080]^T) fused epilogue (M=8192, N=2048, K=2048)
  //     256 blocks = exactly 1 CU-round, chunk cols=4; y -> y_bf (ld 2048)
  gemm256<1><<<256, 512, 0, stream>>>(xc_bf, xb_bf + (size_t)32 * 2048, y_bf,
                                      2048, 2048, 2048, 2048, 2,
                                      xz_bf, Dw, bc_ws);
  // 5) out = y @ W_out^T  (M=8192, N=1024, K=2048), fp32 out — legacy 128^2 (512 blocks)
  gemm_bt<0, 1><<<dim3(64, 8), 256, 0, stream>>>(y_bf, w_bf, out, 1024, 2048, 2048, 2048, 1024);
}

// Round 11
// 325.892 us; speedup vs baseline: 1.0907x; 1.0130x over previous
//
#include <hip/hip_runtime.h>
#include <hip/hip_bf16.h>
#include <cstdint>
#include <cmath>

typedef __bf16 bf16x8 __attribute__((ext_vector_type(8)));
typedef float  f32x4  __attribute__((ext_vector_type(4)));
typedef unsigned short u16x8 __attribute__((ext_vector_type(8)));

#define BT 128   // tile M and N (legacy 128^2 kernel, used for GEMM3)
#define BK 64    // tile K

__device__ __forceinline__ float bf2f(unsigned short h) {
  union { unsigned int u; float f; } v; v.u = ((unsigned int)h) << 16;
  return v.f;
}
__device__ __forceinline__ unsigned short f2bf(float x) {
  union { float f; unsigned int u; } v; v.f = x;
  unsigned int r = v.u + 0x7fffu + ((v.u >> 16) & 1u);  // RNE
  return (unsigned short)(r >> 16);
}

__device__ __forceinline__ void gld_lds16(const void* g, void* l) {
  __builtin_amdgcn_global_load_lds(
      (const __attribute__((address_space(1))) unsigned int*)g,
      (__attribute__((address_space(3))) unsigned int*)l,
      16, 0, 0);
}

__device__ __forceinline__ void cvt4(const float* __restrict__ in,
                                     unsigned short* __restrict__ out, int i) {
  float4 v = reinterpret_cast<const float4*>(in)[i];
  ushort4 o;
  o.x = f2bf(v.x); o.y = f2bf(v.y); o.z = f2bf(v.z); o.w = f2bf(v.w);
  reinterpret_cast<ushort4*>(out)[i] = o;
}

// Head: convert x (8192 blocks) and W_in (4096 blocks) in one launch.
__global__ void cvt_head(const float* __restrict__ x, unsigned short* __restrict__ xb,
                         const float* __restrict__ W_in, unsigned short* __restrict__ wb) {
  int b = blockIdx.x;
  if (b < 8192) cvt4(x, xb, b * 256 + threadIdx.x);
  else          cvt4(W_in, wb, (b - 8192) * 256 + threadIdx.x);
}

// Conv strip: thread owns 8 channels x 8 rows (1024 strips -> 4 blocks/CU;
// the old 32-row/256-block form was latency-exposed at 1 wave/SIMD).
// 3-row history re-read (3/8 overhead) buys 4x the thread-level parallelism.
__device__ void conv_strip8(const unsigned short* __restrict__ xz,
                            const float* __restrict__ conv_w,
                            const float* __restrict__ conv_b,
                            unsigned short* __restrict__ xc,
                            int strip, int tid) {
  const int bl0  = strip * 8;
  const int seq0 = bl0 & ~4095;      // sequence start (B=2, L=4096; 8 | 4096)
  const int c0   = tid * 8;
  float w[4][8], bb[8];
#pragma unroll
  for (int j = 0; j < 8; ++j) {
    float4 wr = reinterpret_cast<const float4*>(conv_w)[c0 + j];
    w[0][j] = wr.x; w[1][j] = wr.y; w[2][j] = wr.z; w[3][j] = wr.w;
    bb[j] = conv_b[c0 + j];
  }
  // Load 3 history rows + 8 current rows; all independent -> batched issue.
  u16x8 rowv[8];
  float win[3][8];
#pragma unroll
  for (int i = 0; i < 3; ++i) {
    int r = bl0 - 3 + i;
    if (r >= seq0) {
      u16x8 v = *reinterpret_cast<const u16x8*>(xz + (size_t)r * 4096 + c0);
#pragma unroll
      for (int j = 0; j < 8; ++j) win[i][j] = bf2f(v[j]);
    } else {
#pragma unroll
      for (int j = 0; j < 8; ++j) win[i][j] = 0.f;
    }
  }
#pragma unroll
  for (int i = 0; i < 8; ++i)
    rowv[i] = *reinterpret_cast<const u16x8*>(xz + (size_t)(bl0 + i) * 4096 + c0);

#pragma unroll
  for (int i = 0; i < 8; ++i) {
    u16x8 o;
#pragma unroll
    for (int j = 0; j < 8; ++j) {
      float cur = bf2f(rowv[i][j]);
      float a = bb[j] + w[0][j] * win[0][j] + w[1][j] * win[1][j]
                      + w[2][j] * win[2][j] + w[3][j] * cur;
      o[j] = f2bf(a * __builtin_amdgcn_rcpf(1.f + __expf(-a)));
      win[0][j] = win[1][j]; win[1][j] = win[2][j]; win[2][j] = cur;
    }
    *reinterpret_cast<u16x8*>(xc + (size_t)(bl0 + i) * 2048 + c0) = o;
  }
}

// Mid: conv_silu (1024 strips) + W_xproj cvt + W_out cvt, one launch.
__global__ void mid_fused(const unsigned short* __restrict__ xz,
                          const float* __restrict__ conv_w,
                          const float* __restrict__ conv_b,
                          unsigned short* __restrict__ xc,
                          const float* __restrict__ W_xproj, unsigned short* __restrict__ wx_bf,
                          const float* __restrict__ W_out,   unsigned short* __restrict__ wo_bf) {
  int b = blockIdx.x;
  if (b < 1024) { conv_strip8(xz, conv_w, conv_b, xc, b, threadIdx.x); return; }
  b -= 1024;
  if (b < 4160) { cvt4(W_xproj, wx_bf, b * 256 + threadIdx.x); return; }
  cvt4(W_out, wo_bf, (b - 4160) * 256 + threadIdx.x);
}

// ---------------------------------------------------------------------------
// Legacy 128^2 kernel (m97 structure) — kept for GEMM3 (N=1024: 512 blocks).
// ---------------------------------------------------------------------------
template <int GUARD_N, int OUT_F32>
__global__ __launch_bounds__(256, 2)
void gemm_bt(const unsigned short* __restrict__ A,
             const unsigned short* __restrict__ B,
             void* __restrict__ Cv,
             int N, int K, int ldA, int ldB, int ldC)
{
  __shared__ __align__(16) unsigned short sA[BT * BK];
  __shared__ __align__(16) unsigned short sB[BT * BK];

  const int tid  = threadIdx.x;
  const int lane = tid & 63;
  const int wave = tid >> 6;
  const int row0 = blockIdx.x * BT;
  const int col0 = blockIdx.y * BT;

  const int wrow = (wave & 1) * 64;
  const int wcol = (wave >> 1) * 64;
  const int l15  = lane & 15;
  const int q    = lane >> 4;

  f32x4 acc[4][4];
#pragma unroll
  for (int i = 0; i < 4; ++i)
#pragma unroll
    for (int j = 0; j < 4; ++j)
      acc[i][j] = (f32x4){0.f, 0.f, 0.f, 0.f};

  const int nk = K / BK;
  for (int kt = 0; kt < nk; ++kt) {
    const int k0 = kt * BK;
#pragma unroll
    for (int t = 0; t < 4; ++t) {
      int c  = t * 256 + tid;
      int r  = c >> 3;
      int g  = c & 7;
      int gs = (g ^ (r & 7)) * 8;
      gld_lds16(A + (size_t)(row0 + r) * ldA + k0 + gs, (void*)(sA + c * 8));
      int br = col0 + r;
      if (GUARD_N) br = (br < N) ? br : (N - 1);
      gld_lds16(B + (size_t)br * ldB + k0 + gs, (void*)(sB + c * 8));
    }
    __syncthreads();

#pragma unroll
    for (int kk = 0; kk < BK; kk += 32) {
      const int grb = kk >> 3;
      bf16x8 af[4], bfr[4];
#pragma unroll
      for (int i = 0; i < 4; ++i) {
        int ar = wrow + i * 16 + l15;
        af[i] = *reinterpret_cast<const bf16x8*>(
            sA + ar * BK + (((grb + q) ^ (ar & 7)) << 3));
        int br = wcol + i * 16 + l15;
        bfr[i] = *reinterpret_cast<const bf16x8*>(
            sB + br * BK + (((grb + q) ^ (br & 7)) << 3));
      }
#pragma unroll
      for (int i = 0; i < 4; ++i)
#pragma unroll
        for (int j = 0; j < 4; ++j)
          acc[i][j] = __builtin_amdgcn_mfma_f32_16x16x32_bf16(af[i], bfr[j], acc[i][j], 0, 0, 0);
    }
    __syncthreads();
  }

#pragma unroll
  for (int i = 0; i < 4; ++i) {
#pragma unroll
    for (int j = 0; j < 4; ++j) {
      int colw = col0 + wcol + j * 16 + l15;
      if (GUARD_N && colw >= N) continue;
#pragma unroll
      for (int r = 0; r < 4; ++r) {
        int roww = row0 + wrow + i * 16 + q * 4 + r;
        if (OUT_F32)
          ((float*)Cv)[(size_t)roww * ldC + colw] = acc[i][j][r];
        else
          ((unsigned short*)Cv)[(size_t)roww * ldC + colw] = f2bf(acc[i][j][r]);
      }
    }
  }
}

// ---------------------------------------------------------------------------
// 256x256 8-phase GEMM — R5/R8-verified K-loop (8 barriers/K-tile, no spill)
// + chunked XCD swizzle + conflict-free LDS epilogue.
// EPI=0: plain bf16 C store. EPI=1 (GEMM2): fused gate epilogue,
// latency-pipelined (R10-verified): first xc/z/bc batch + D row issued
// BEFORE the barrier; 2-deep prefetch loop; silu via v_rcp.
// ---------------------------------------------------------------------------
#define BARX() do { __builtin_amdgcn_sched_barrier(0); \
                    __builtin_amdgcn_s_barrier(); \
                    __builtin_amdgcn_sched_barrier(0); } while (0)
#define VMW(n) asm volatile("s_waitcnt vmcnt(" #n ")" ::: "memory")
#define LGKM0() asm volatile("s_waitcnt lgkmcnt(0)" ::: "memory")

#define STAGE_A(b, h, kt) do { \
  const unsigned short* _p = Ab + (size_t)((h) * 128) * ldA + (kt) * 64; \
  gld_lds16(_p,                     (void*)&sA[b][((h) * 128      + rr) * 64 + (g8 << 3)]); \
  gld_lds16(_p + (size_t)64 * ldA,  (void*)&sA[b][((h) * 128 + 64 + rr) * 64 + (g8 << 3)]); \
} while (0)

#define STAGE_B(b, h, kt) do { \
  const unsigned short* _p = Bb + (size_t)((h) * 128) * ldB + (kt) * 64; \
  gld_lds16(_p,                     (void*)&sB[b][((h) * 128      + rr) * 64 + (g8 << 3)]); \
  gld_lds16(_p + (size_t)64 * ldB,  (void*)&sB[b][((h) * 128 + 64 + rr) * 64 + (g8 << 3)]); \
} while (0)

#define RD_A_SET(dst, b, p) do { \
  dst[0][0] = *reinterpret_cast<const bf16x8*>(&sA[b][aOff + (2*(p)    ) * 1024 + kph0]); \
  dst[0][1] = *reinterpret_cast<const bf16x8*>(&sA[b][aOff + (2*(p)    ) * 1024 + kph1]); \
  dst[1][0] = *reinterpret_cast<const bf16x8*>(&sA[b][aOff + (2*(p) + 1) * 1024 + kph0]); \
  dst[1][1] = *reinterpret_cast<const bf16x8*>(&sA[b][aOff + (2*(p) + 1) * 1024 + kph1]); \
} while (0)

#define RD_B_SET(dst, b) do { \
  dst[0][0] = *reinterpret_cast<const bf16x8*>(&sB[b][bOff + 0 * 1024 + kph0]); \
  dst[0][1] = *reinterpret_cast<const bf16x8*>(&sB[b][bOff + 0 * 1024 + kph1]); \
  dst[1][0] = *reinterpret_cast<const bf16x8*>(&sB[b][bOff + 1 * 1024 + kph0]); \
  dst[1][1] = *reinterpret_cast<const bf16x8*>(&sB[b][bOff + 1 * 1024 + kph1]); \
  dst[2][0] = *reinterpret_cast<const bf16x8*>(&sB[b][bOff + 2 * 1024 + kph0]); \
  dst[2][1] = *reinterpret_cast<const bf16x8*>(&sB[b][bOff + 2 * 1024 + kph1]); \
  dst[3][0] = *reinterpret_cast<const bf16x8*>(&sB[b][bOff + 3 * 1024 + kph0]); \
  dst[3][1] = *reinterpret_cast<const bf16x8*>(&sB[b][bOff + 3 * 1024 + kph1]); \
} while (0)

#define MMA(i, j, k, Af, Bf) \
  acc[i][j] = __builtin_amdgcn_mfma_f32_16x16x32_bf16(Af[(i) & 1][k], Bf[j][k], acc[i][j], 0, 0, 0)

// 16 MFMA, dependency distance 8: all 8 accs at k-half 0, then k-half 1.
#define MFMA_PH(p, Af, Bf) do { \
  __builtin_amdgcn_s_setprio(1); \
  MMA(2*(p),   0, 0, Af, Bf); MMA(2*(p),   1, 0, Af, Bf); \
  MMA(2*(p),   2, 0, Af, Bf); MMA(2*(p),   3, 0, Af, Bf); \
  MMA(2*(p)+1, 0, 0, Af, Bf); MMA(2*(p)+1, 1, 0, Af, Bf); \
  MMA(2*(p)+1, 2, 0, Af, Bf); MMA(2*(p)+1, 3, 0, Af, Bf); \
  MMA(2*(p),   0, 1, Af, Bf); MMA(2*(p),   1, 1, Af, Bf); \
  MMA(2*(p),   2, 1, Af, Bf); MMA(2*(p),   3, 1, Af, Bf); \
  MMA(2*(p)+1, 0, 1, Af, Bf); MMA(2*(p)+1, 1, 1, Af, Bf); \
  MMA(2*(p)+1, 2, 1, Af, Bf); MMA(2*(p)+1, 3, 1, Af, Bf); \
  __builtin_amdgcn_s_setprio(0); \
} while (0)

template <int EPI>
__global__ __launch_bounds__(512, 2)
void gemm256(const unsigned short* __restrict__ A,
             const unsigned short* __restrict__ B,
             unsigned short* __restrict__ C,
             int K, int ldA, int ldB, int ldC, int ccsh,
             const unsigned short* __restrict__ XZ,  // EPI=1: z at col 2048+
             const float* __restrict__ Dw,           // EPI=1: D[2048]
             const float* __restrict__ BC)           // EPI=1: bc[8192]
{
  __shared__ __align__(16) unsigned short smem[4 * 256 * 64];  // 128 KiB
  unsigned short (*sA)[256 * 64] = (unsigned short (*)[256 * 64])smem;
  unsigned short (*sB)[256 * 64] = (unsigned short (*)[256 * 64])(smem + 2 * 256 * 64);

  const int tid  = threadIdx.x;
  const int lane = tid & 63;
  const int wave = tid >> 6;
  const int wm = wave >> 2;      // 0..1
  const int wn = wave & 3;       // 0..3
  const int l15 = lane & 15;
  const int q   = lane >> 4;

  // Chunked XCD swizzle: XCD x owns an R x CC chunk of output tiles;
  // XCD grid = 2 chunk-cols x 4 chunk-rows. Bijective for nwg%8==0.
  const int nwg = gridDim.x;
  const int wg  = blockIdx.x;
  const int x   = wg & 7;
  const int c   = wg >> 3;
  const int CC  = 1 << ccsh;
  const int R   = (nwg >> 3) >> ccsh;
  const int row0 = ((x >> 1) * R + (c >> ccsh)) * 256;
  const int col0 = ((x & 1) * CC + (c & (CC - 1))) * 256;

  // staging geometry: thread covers row rr (+64 per 2nd load), k-group g8;
  // LDS slot (r,g) holds global k-group g^(r&7) -> pre-swizzled global source
  const int rr  = tid >> 3;
  const int g8  = tid & 7;
  const int gsw = ((g8 ^ (rr & 7)) << 3);
  const unsigned short* Ab = A + (size_t)(row0 + rr) * ldA + gsw;
  const unsigned short* Bb = B + (size_t)(col0 + rr) * ldB + gsw;

  // ds-read geometry
  const int aOff = (wm * 128 + l15) * 64;
  const int bOff = (wn * 64  + l15) * 64;
  const int a7   = l15 & 7;
  const int kph0 = ((q       ^ a7) << 3);  // k-groups 0..3 (kk=0)
  const int kph1 = (((4 + q) ^ a7) << 3);  // k-groups 4..7 (kk=32)

  f32x4 acc[8][4];
#pragma unroll
  for (int i = 0; i < 8; ++i)
#pragma unroll
    for (int j = 0; j < 4; ++j)
      acc[i][j] = (f32x4){0.f, 0.f, 0.f, 0.f};

  bf16x8 afe[2][2], afo[2][2];   // A fragments, phase-parity double buffer
  bf16x8 bfe[4][2], bfo[4][2];   // B fragments, K-tile-parity double buffer

  const int nk = K >> 6;
  // Prologue: tile0 A+B into buf0, tile1 B into buf1 (12 loads); wait tile0,
  // then prime registers for even-tile phase 0.
  STAGE_A(0, 0, 0); STAGE_A(0, 1, 0);
  STAGE_B(0, 0, 0); STAGE_B(0, 1, 0);
  STAGE_B(1, 0, 1); STAGE_B(1, 1, 1);
  VMW(4);
  BARX();
  RD_B_SET(bfe, 0); RD_A_SET(afe, 0, 0);

  const int niter = K >> 7;
  for (int it = 0; it < niter; ++it) {
    const int kt1 = 2 * it + 1;
    int ktE = 2 * it + 2; if (ktE > nk - 1) ktE = nk - 1;  // clamped tail restage
    int ktO = 2 * it + 3; if (ktO > nk - 1) ktO = nk - 1;

    // ---- even K-tile (buf0, bfe) ----
    STAGE_A(1, 0, kt1);
    BARX();
    MFMA_PH(0, afe, bfe); RD_A_SET(afo, 0, 1);
    BARX();
    STAGE_A(1, 1, kt1);
    BARX();
    MFMA_PH(1, afo, bfe); RD_A_SET(afe, 0, 2);
    BARX();
    STAGE_B(0, 0, ktE);
    BARX();
    MFMA_PH(2, afe, bfe); RD_A_SET(afo, 0, 3);
    BARX();
    STAGE_B(0, 1, ktE);
    VMW(4);
    BARX();
    MFMA_PH(3, afo, bfe); RD_B_SET(bfo, 1); RD_A_SET(afe, 1, 0);
    BARX();

    // ---- odd K-tile (buf1, bfo) ----
    STAGE_A(0, 0, ktE);
    BARX();
    MFMA_PH(0, afe, bfo); RD_A_SET(afo, 1, 1);
    BARX();
    STAGE_A(0, 1, ktE);
    BARX();
    MFMA_PH(1, afo, bfo); RD_A_SET(afe, 1, 2);
    BARX();
    STAGE_B(1, 0, ktO);
    BARX();
    MFMA_PH(2, afe, bfo); RD_A_SET(afo, 1, 3);
    BARX();
    STAGE_B(1, 1, ktO);
    VMW(4);
    BARX();
    MFMA_PH(3, afo, bfo); RD_B_SET(bfe, 0); RD_A_SET(afe, 0, 0);
    BARX();
  }

  // ---- Epilogue: drain, stage C tile in LDS (q-XOR, conflict-free), then
  //      coalesced store (EPI=0) or fused gate + y store (EPI=1). ----
  VMW(0);
  LGKM0();
  BARX();
  {
    unsigned short* cs = smem;  // 65536 ushorts = one 256x256 bf16 C tile
#pragma unroll
    for (int i = 0; i < 8; ++i) {
      const int row = wm * 128 + i * 16 + q * 4;
#pragma unroll
      for (int j = 0; j < 4; ++j) {
        const int col = (wn * 64 + j * 16 + l15) ^ (q << 4);
#pragma unroll
        for (int r = 0; r < 4; ++r)
          cs[(row + r) * 256 + col] = f2bf(acc[i][j][r]);
      }
    }

    const int colf   = (tid * 8) & 255;   // fixed col-chunk per thread
    const int rowofs = tid >> 5;          // 0..15
    const int colX   = col0 + colf;

    if (EPI == 0) {
      LGKM0();   // ds_writes committed before signaling
      BARX();
#pragma unroll
      for (int s = 0; s < 16; ++s) {
        const int row  = s * 16 + rowofs;
        const int rcol = colf ^ (((row >> 2) & 3) << 4);  // inverse write XOR
        u16x8 v = *reinterpret_cast<const u16x8*>(&cs[row * 256 + rcol]);
        *reinterpret_cast<u16x8*>(C + (size_t)(row0 + row) * ldC + colX) = v;
      }
    } else {
      // Issue D row + first xc/z/bc batch BEFORE the barrier: acc is dead,
      // barrier latency covers the first HBM round trip.
      float dj[8];
      float4 d0 = reinterpret_cast<const float4*>(Dw)[colX >> 2];
      float4 d1 = reinterpret_cast<const float4*>(Dw)[(colX >> 2) + 1];
      dj[0] = d0.x; dj[1] = d0.y; dj[2] = d0.z; dj[3] = d0.w;
      dj[4] = d1.x; dj[5] = d1.y; dj[6] = d1.z; dj[7] = d1.w;
      const size_t g0 = (size_t)(row0 + rowofs);
      u16x8 xc_c = *reinterpret_cast<const u16x8*>(A + g0 * ldA + colX);
      u16x8 zv_c = *reinterpret_cast<const u16x8*>(XZ + g0 * 4096 + 2048 + colX);
      float bc_c = BC[g0];

      LGKM0();   // ds_writes committed before signaling
      BARX();

      // 2-deep pipeline: prefetch batch s+1, consume batch s.
#pragma unroll
      for (int s = 0; s < 16; ++s) {
        u16x8 xc_n, zv_n; float bc_n;
        if (s < 15) {
          const size_t gn = (size_t)(row0 + (s + 1) * 16 + rowofs);
          xc_n = *reinterpret_cast<const u16x8*>(A + gn * ldA + colX);
          zv_n = *reinterpret_cast<const u16x8*>(XZ + gn * 4096 + 2048 + colX);
          bc_n = BC[gn];
        }
        const int row  = s * 16 + rowofs;
        const int rcol = colf ^ (((row >> 2) & 3) << 4);
        const size_t gr = (size_t)(row0 + row);
        u16x8 pv = *reinterpret_cast<const u16x8*>(&cs[row * 256 + rcol]);
        u16x8 o;
#pragma unroll
        for (int j = 0; j < 8; ++j) {
          float p  = bf2f(pv[j]);
          float delta = (p > 15.f) ? p : __logf(1.f + __expf(p));
          float xv = bf2f(xc_c[j]);
          float zz = bf2f(zv_c[j]);
          float y  = delta * xv * bc_c + dj[j] * xv;
          y *= zz * __builtin_amdgcn_rcpf(1.f + __expf(-zz));
          o[j] = f2bf(y);
        }
        *reinterpret_cast<u16x8*>(C + gr * ldC + colX) = o;
        if (s < 15) { xc_c = xc_n; zv_c = zv_n; bc_c = bc_n; }
      }
    }
  }
}

// ---------------------------------------------------------------------------
// proj strip -> bc: bc[row] = sum_s B[row][s]*C[row][s] where B,C are
// proj cols 0..15 / 16..31 (never materialized). 16 rows/block x 512 blocks
// (2 blocks/CU — the old 32-row/256-block form was latency-exposed).
// ---------------------------------------------------------------------------
__global__ __launch_bounds__(256)
void proj_strip(const unsigned short* __restrict__ xc,   // [8192][2048]
                const unsigned short* __restrict__ wx,   // [2080][2048], rows 0..31
                float* __restrict__ bc)                  // [8192]
{
  __shared__ float red[4][16 * 33];
  const int tid  = threadIdx.x;
  const int lane = tid & 63;
  const int wave = tid >> 6;
  const int l15  = lane & 15;
  const int q    = lane >> 4;
  const int row0 = blockIdx.x * 16;

  f32x4 acc[2];
  acc[0] = (f32x4){0.f, 0.f, 0.f, 0.f};
  acc[1] = (f32x4){0.f, 0.f, 0.f, 0.f};

  const int kbase = wave * 512;
#pragma unroll 4
  for (int kk = 0; kk < 512; kk += 32) {
    const int k = kbase + kk + q * 8;
    bf16x8 a0 = *reinterpret_cast<const bf16x8*>(&xc[(size_t)(row0 + l15) * 2048 + k]);
    bf16x8 b0 = *reinterpret_cast<const bf16x8*>(&wx[(size_t)(l15) * 2048 + k]);
    bf16x8 b1 = *reinterpret_cast<const bf16x8*>(&wx[(size_t)(16 + l15) * 2048 + k]);
    acc[0] = __builtin_amdgcn_mfma_f32_16x16x32_bf16(a0, b0, acc[0], 0, 0, 0);
    acc[1] = __builtin_amdgcn_mfma_f32_16x16x32_bf16(a0, b1, acc[1], 0, 0, 0);
  }

  // C/D layout: col=lane&15 (proj col within half), row=q*4+reg (xc row)
#pragma unroll
  for (int j = 0; j < 2; ++j)
#pragma unroll
    for (int r = 0; r < 4; ++r)
      red[wave][(q * 4 + r) * 33 + j * 16 + l15] = acc[j][r];
  __syncthreads();

  if (tid < 16) {
    float s = 0.f;
#pragma unroll
    for (int cc = 0; cc < 16; ++cc) {
      const int ib = tid * 33 + cc;
      float b  = red[0][ib] + red[1][ib] + red[2][ib] + red[3][ib];
      float cv = red[0][ib + 16] + red[1][ib + 16] + red[2][ib + 16] + red[3][ib + 16];
      s += b * cv;
    }
    bc[row0 + tid] = s;
  }
}

extern "C" void kernel_launch(void* const* d_in, const int* in_sizes, int n_in,
                              void* d_out, int out_size, void* d_ws, size_t ws_size,
                              hipStream_t stream) {
  const float* x       = (const float*)d_in[0]; // [8192][1024]
  const float* W_in    = (const float*)d_in[1]; // [4096][1024]
  const float* conv_w  = (const float*)d_in[2]; // [2048][4]
  const float* conv_b  = (const float*)d_in[3]; // [2048]
  const float* W_xproj = (const float*)d_in[4]; // [2080][2048]
  const float* Dw      = (const float*)d_in[5]; // [2048]
  const float* W_out   = (const float*)d_in[6]; // [1024][2048]
  float* out = (float*)d_out;                   // [8192][1024] fp32

  // Workspace layout (bf16 buffers)
  unsigned short* xz_bf   = (unsigned short*)d_ws;                 // 8192*4096
  unsigned short* xc_bf   = xz_bf  + (size_t)8192 * 4096;          // 8192*2048
  unsigned short* y_bf    = xc_bf  + (size_t)8192 * 2048;          // 8192*2048 (old proj region)
  float*          bc_ws   = (float*)(y_bf + (size_t)8192 * 2048);  // 8192 fp32 (proj slack)
  unsigned short* xb_bf   = y_bf + (size_t)8192 * 2080;            // 8192*1024 (reused for W_xproj)
  unsigned short* w_bf    = xb_bf  + (size_t)8192 * 1024;          // 4096*1024 (reused for W_out)

  // 1) convert x + W_in
  cvt_head<<<8192 + 4096, 256, 0, stream>>>(x, xb_bf, W_in, w_bf);
  // 2) xz = x @ W_in^T   (M=8192, N=4096, K=1024) — 512 blocks, chunk cols=8
  gemm256<0><<<512, 512, 0, stream>>>(xb_bf, w_bf, xz_bf, 1024, 1024, 1024, 4096, 3,
                                      nullptr, nullptr, nullptr);
  // 3) conv+silu -> xc (1024 strips), W_xproj -> xb region, W_out -> w_bf region
  mid_fused<<<1024 + 4160 + 2048, 256, 0, stream>>>(xz_bf, conv_w, conv_b, xc_bf,
                                                    W_xproj, xb_bf, W_out, w_bf);
  // 4a) bc[row] = proj[:,0:16] . proj[:,16:32] directly from xc @ W_xproj[0:32]^T
  proj_strip<<<512, 256, 0, stream>>>(xc_bf, xb_bf, bc_ws);
  // 4b) y = gate(xc @ W_xproj[32:2080]^T) fused epilogue (M=8192, N=2048, K=2048)
  //     256 blocks = exactly 1 CU-round, chunk cols=4; y -> y_bf (ld 2048)
  gemm256<1><<<256, 512, 0, stream>>>(xc_bf, xb_bf + (size_t)32 * 2048, y_bf,
                                      2048, 2048, 2048, 2048, 2,
                                      xz_bf, Dw, bc_ws);
  // 5) out = y @ W_out^T  (M=8192, N=1024, K=2048), fp32 out — legacy 128^2 (512 blocks)
  gemm_bt<0, 1><<<dim3(64, 8), 256, 0, stream>>>(y_bf, w_bf, out, 1024, 2048, 2048, 2048, 1024);
}